// Round 9
// baseline (179.020 us; speedup 1.0000x reference)
//
#include <hip/hip_runtime.h>
#include <hip/hip_bf16.h>
#include <math.h>

#define TOK   8192
#define HDIM  1024
#define NE    16
#define NI    512
#define F2    1024
#define CAP   8192
#define CAP2  2048
#define ALPHA 1.702f
#define LIMIT 7.0f

typedef __attribute__((ext_vector_type(8))) short short8;
typedef __attribute__((ext_vector_type(4))) short short4v;
typedef __attribute__((ext_vector_type(4))) float f32x4;

static __device__ __forceinline__ unsigned short f2bf(float f) {
    unsigned int u = __float_as_uint(f);
    u += 0x7FFFu + ((u >> 16) & 1u);
    return (unsigned short)(u >> 16);
}
static __device__ __forceinline__ float bf2f(unsigned short u) {
    return __uint_as_float((unsigned int)u << 16);
}

#define GLD_LDS16(g, l) __builtin_amdgcn_global_load_lds(                     \
    (const __attribute__((address_space(1))) void*)(g),                       \
    (__attribute__((address_space(3))) void*)(l), 16, 0, 0)

// ================= router phase A: fp64 partial logits, fused x->bf16 =================
__global__ __launch_bounds__(64) void router_partial_kernel(
    const float* __restrict__ x, const float* __restrict__ rw,
    double* __restrict__ part, unsigned short* __restrict__ xbf)
{
    int bx = blockIdx.x;
    int tile = bx >> 2, ksl = bx & 3;
    int t0 = tile * 16;
    int hbase = ksl * 256;

    __shared__ __align__(16) float sx[16][68];
    __shared__ __align__(16) float srw[64][16];

    int lane = threadIdx.x;
    int tt = lane & 15, eg = lane >> 4;

    double acc[4] = {0.0, 0.0, 0.0, 0.0};

    for (int hc = 0; hc < 4; ++hc) {
        int h0 = hbase + hc * 64;
        __syncthreads();
#pragma unroll
        for (int j = 0; j < 4; ++j) {
            int fidx = j * 64 + lane;
            int t = fidx >> 4, c4 = (fidx & 15) * 4;
            float4 v = *(const float4*)(x + (size_t)(t0 + t) * HDIM + h0 + c4);
            *(float4*)&sx[t][c4] = v;
            short4v s;
            s[0] = (short)f2bf(v.x); s[1] = (short)f2bf(v.y);
            s[2] = (short)f2bf(v.z); s[3] = (short)f2bf(v.w);
            *(short4v*)(xbf + (size_t)(t0 + t) * HDIM + h0 + c4) = s;
        }
#pragma unroll
        for (int j = 0; j < 4; ++j) {
            int ridx = j * 64 + lane;
            int h = ridx >> 2, e4 = (ridx & 3) * 4;
            float4 v = *(const float4*)(rw + (size_t)(h0 + h) * NE + e4);
            *(float4*)&srw[h][e4] = v;
        }
        __syncthreads();
#pragma unroll 8
        for (int j = 0; j < 64; ++j) {
            float xv = sx[tt][j];
            float4 wv = *(const float4*)&srw[j][eg * 4];
            double xd = (double)xv;
            acc[0] += xd * (double)wv.x;
            acc[1] += xd * (double)wv.y;
            acc[2] += xd * (double)wv.z;
            acc[3] += xd * (double)wv.w;
        }
    }
#pragma unroll
    for (int q = 0; q < 4; ++q)
        part[(size_t)(ksl * NE + eg * 4 + q) * TOK + t0 + tt] = acc[q];
}

// ===== router phase B: combine, top-2, softmax, aggregated scatter + inverse map =====
__global__ __launch_bounds__(256) void router_combine_kernel(
    const double* __restrict__ part,
    int* __restrict__ counts, int* __restrict__ toks, float* __restrict__ wgts,
    unsigned short* __restrict__ inv)
{
    __shared__ int lhist[NE];
    __shared__ int lbase[NE];
    int tid = threadIdx.x;
    int t = blockIdx.x * 256 + tid;
    if (tid < NE) lhist[tid] = 0;
    __syncthreads();

    double acc[NE];
#pragma unroll
    for (int e = 0; e < NE; ++e)
        acc[e] = part[(size_t)(0 * NE + e) * TOK + t]
               + part[(size_t)(1 * NE + e) * TOK + t]
               + part[(size_t)(2 * NE + e) * TOK + t]
               + part[(size_t)(3 * NE + e) * TOK + t];

    int i0 = 0; double v0 = acc[0];
#pragma unroll
    for (int e = 1; e < NE; ++e) if (acc[e] > v0) { v0 = acc[e]; i0 = e; }
    int i1 = -1; double v1 = -1e300;
#pragma unroll
    for (int e = 0; e < NE; ++e) if (e != i0 && acc[e] > v1) { v1 = acc[e]; i1 = e; }
    double e1 = exp(v1 - v0);
    float w0 = (float)(1.0 / (1.0 + e1));
    float w1 = (float)(e1 / (1.0 + e1));

    int r0 = atomicAdd(&lhist[i0], 1);
    int r1 = atomicAdd(&lhist[i1], 1);
    __syncthreads();
    if (tid < NE) lbase[tid] = atomicAdd(&counts[tid], lhist[tid]);
    __syncthreads();
    int p0 = lbase[i0] + r0; if (p0 > 2047) p0 = 2047;
    int p1 = lbase[i1] + r1; if (p1 > 2047) p1 = 2047;
    toks[i0 * CAP + p0] = t; wgts[i0 * CAP + p0] = w0;
    toks[i1 * CAP + p1] = t; wgts[i1 * CAP + p1] = w1;
    inv[2 * t]     = (unsigned short)((i0 << 11) | p0);
    inv[2 * t + 1] = (unsigned short)((i1 << 11) | p1);
}

// ------------- transpose + convert: in [E][R][C] fp32 -> out [E][C][R] bf16 -------------
__global__ __launch_bounds__(256) void transpose_kernel(
    const float* __restrict__ in, unsigned short* __restrict__ out, int R, int C, int perm)
{
    int e = blockIdx.z;
    const float* pin = in + (size_t)e * R * C;
    unsigned short* pout = out + (size_t)e * R * C;
    __shared__ float t2[64][65];
    int c0 = blockIdx.x * 64, r0 = blockIdx.y * 64;
    int tid = threadIdx.x;
#pragma unroll
    for (int j = 0; j < 4; ++j) {
        int idx4 = j * 256 + tid;
        int r = idx4 >> 4, c4 = (idx4 & 15) * 4;
        float4 v = *(const float4*)(pin + (size_t)(r0 + r) * C + c0 + c4);
        t2[c4 + 0][r] = v.x;
        t2[c4 + 1][r] = v.y;
        t2[c4 + 2][r] = v.z;
        t2[c4 + 3][r] = v.w;
    }
    __syncthreads();
#pragma unroll
    for (int j = 0; j < 2; ++j) {
        int idx = j * 256 + tid;
        int n = idx >> 3, k0 = (idx & 7) * 8;
        short8 v;
#pragma unroll
        for (int q = 0; q < 8; ++q) v[q] = (short)f2bf(t2[n][k0 + q]);
        int c = c0 + n;
        int orow;
        if (perm) {
            int tile = c >> 7, ct = c & 127;
            int fl = ct >> 1, h = ct & 1;
            orow = (tile << 7) | ((fl >> 4) << 5) | (h << 4) | (fl & 15);
        } else {
            orow = c;
        }
        *(short8*)(pout + (size_t)orow * R + r0 + k0) = v;
    }
}

// ===== BM=256 x BN=128 x BK=32, 512 thr (8 waves 4Mx2N); 3-buf depth-2 counted vmcnt =====
// Per thread per tile: 2 A-loads + 1 B-load -> in flight after issue = 6 (2 tiles).
#define STAGE_TILE(buf, kidx)                                                         \
    GLD_LDS16(gaA[0] + (size_t)(kidx) * 32, &As[buf][w * 32][0]);                     \
    GLD_LDS16(gaA[1] + (size_t)(kidx) * 32, &As[buf][w * 32 + 16][0]);                \
    GLD_LDS16(gaB0   + (size_t)(kidx) * 32, &Bs[buf][w * 16][0]);

#define KLOOP_BODY(NT)                                                                \
    int cb = 0;                                                                       \
    for (int kb = 0; kb < (NT); ++kb) {                                               \
        if (kb + 2 < (NT)) {                                                          \
            int cpre = cb + 2; if (cpre >= 3) cpre -= 3;                              \
            STAGE_TILE(cpre, kb + 2)                                                  \
            asm volatile("s_waitcnt vmcnt(6)" ::: "memory");                          \
        } else if (kb + 1 < (NT)) {                                                   \
            asm volatile("s_waitcnt vmcnt(3)" ::: "memory");                          \
        } else {                                                                      \
            asm volatile("s_waitcnt vmcnt(0)" ::: "memory");                          \
        }                                                                             \
        __builtin_amdgcn_sched_barrier(0);                                            \
        __builtin_amdgcn_s_barrier();                                                 \
        __builtin_amdgcn_sched_barrier(0);                                            \
        short8 af[4], bfr[4];                                                         \
        _Pragma("unroll")                                                             \
        for (int m = 0; m < 4; ++m) af[m] = *(const short8*)&As[cb][wr * 64 + m * 16 + lr][slt]; \
        _Pragma("unroll")                                                             \
        for (int n = 0; n < 4; ++n) bfr[n] = *(const short8*)&Bs[cb][wc * 64 + n * 16 + lr][slt]; \
        _Pragma("unroll")                                                             \
        for (int m = 0; m < 4; ++m)                                                   \
            _Pragma("unroll")                                                         \
            for (int n = 0; n < 4; ++n)                                               \
                acc[m][n] = __builtin_amdgcn_mfma_f32_16x16x32_bf16(af[m], bfr[n], acc[m][n], 0, 0, 0); \
        asm volatile("s_waitcnt lgkmcnt(0)" ::: "memory");                            \
        __builtin_amdgcn_sched_barrier(0);                                            \
        __builtin_amdgcn_s_barrier();                                                 \
        __builtin_amdgcn_sched_barrier(0);                                            \
        cb = (cb + 1 == 3) ? 0 : cb + 1;                                              \
    }

// ---------------- GEMM1: x_bf (gathered) @ gupT^T + bias -> act (bf16) ----------------
__global__ __launch_bounds__(512) void gemm1_kernel(
    const unsigned short* __restrict__ xb, const unsigned short* __restrict__ gupT,
    const float* __restrict__ gub,
    const int* __restrict__ counts, const int* __restrict__ toks,
    unsigned short* __restrict__ act, const unsigned short* __restrict__ zp)
{
    int b = blockIdx.x;
    int e = b & 15;
    int j = b >> 4;
    int nt = j & 7;       // N tile: 128 gup cols
    int mt = j >> 3;      // M tile: 256 rows
    int cnt = counts[e];
    int row0 = mt * 256;
    if (row0 >= cnt) return;
    int n0 = nt * 128;

    __shared__ __align__(16) unsigned short As[3][256][32];
    __shared__ __align__(16) unsigned short Bs[3][128][32];
    __shared__ int rtok[256];

    int tid = threadIdx.x;
    int lane = tid & 63;
    int w = tid >> 6;                 // 0..7
    int wr = w >> 1, wc = w & 1;      // 4M x 2N wave grid
    int lr = lane & 15, lg = lane >> 4;

    if (tid < 256) {
        int p = row0 + tid;
        rtok[tid] = (p < cnt) ? toks[e * CAP + p] : -1;
    }
    __syncthreads();

    int srow = lane >> 2;
    int scol = (((lane & 3) ^ ((lane >> 3) & 3)) * 8);   // source-side XOR swizzle
    int slt  = (lg ^ ((lr >> 1) & 3)) * 8;               // read-side

    const unsigned short* gaA[2];
    const unsigned short* gaB0;
    const unsigned short* gupE = gupT + (size_t)e * HDIM * F2;
#pragma unroll
    for (int i = 0; i < 2; ++i) {
        int arow = w * 32 + i * 16 + srow;
        int tk = rtok[arow];
        gaA[i] = (tk >= 0) ? (xb + (size_t)tk * HDIM + scol) : (zp + scol);
    }
    {
        int brow = n0 + w * 16 + srow;
        gaB0 = gupE + (size_t)brow * HDIM + scol;
    }

    f32x4 acc[4][4];
#pragma unroll
    for (int m = 0; m < 4; ++m)
#pragma unroll
        for (int n = 0; n < 4; ++n) acc[m][n] = (f32x4){0.f, 0.f, 0.f, 0.f};

    STAGE_TILE(0, 0)
    STAGE_TILE(1, 1)
    KLOOP_BODY(HDIM / 32)

    // epilogue: permuted B rows => acc[m][2q]=gate, acc[m][2q+1]=up of SAME feature, same lane
    unsigned short* actE = act + (size_t)e * CAP2 * NI;
    int fbase = nt * 64 + wc * 32;
#pragma unroll
    for (int q = 0; q < 2; ++q) {
        int f = fbase + q * 16 + lr;
        float bg = gub[e * F2 + 2 * f];
        float bu = gub[e * F2 + 2 * f + 1];
#pragma unroll
        for (int m = 0; m < 4; ++m) {
#pragma unroll
            for (int r = 0; r < 4; ++r) {
                float gate = acc[m][2 * q][r] + bg;
                float up   = acc[m][2 * q + 1][r] + bu;
                gate = fminf(gate, LIMIT);
                up   = fminf(fmaxf(up, -LIMIT), LIMIT);
                float glu = gate / (1.0f + __expf(-ALPHA * gate));
                float av  = (up + 1.0f) * glu;
                int row = row0 + wr * 64 + m * 16 + lg * 4 + r;
                actE[(size_t)row * NI + f] = f2bf(av);
            }
        }
    }
}

// ------- GEMM2 (tier A): act @ dwnT^T, *score, +bias -> compact bf16 y[base[e]+p][HDIM] -------
__global__ __launch_bounds__(512) void gemm2_y_kernel(
    const unsigned short* __restrict__ act, const unsigned short* __restrict__ dwnT,
    const float* __restrict__ dwb,
    const int* __restrict__ counts, const float* __restrict__ wgts,
    unsigned short* __restrict__ y)
{
    int b = blockIdx.x;
    int e = b & 15;
    int j = b >> 4;
    int nt = j & 7;       // N tile: 128 h cols
    int mt = j >> 3;      // M tile: 256 rows
    int cnt = counts[e];
    int row0 = mt * 256;
    if (row0 >= cnt) return;
    int n0 = nt * 128;

    int base_e = 0;
#pragma unroll
    for (int q = 0; q < NE; ++q) base_e += (q < e) ? counts[q] : 0;

    __shared__ __align__(16) unsigned short As[3][256][32];
    __shared__ __align__(16) unsigned short Bs[3][128][32];
    __shared__ float rwgt[256];

    int tid = threadIdx.x;
    int lane = tid & 63;
    int w = tid >> 6;
    int wr = w >> 1, wc = w & 1;
    int lr = lane & 15, lg = lane >> 4;

    if (tid < 256) {
        int p = row0 + tid;
        rwgt[tid] = (p < cnt) ? wgts[e * CAP + p] : 0.0f;
    }
    __syncthreads();

    int srow = lane >> 2;
    int scol = (((lane & 3) ^ ((lane >> 3) & 3)) * 8);
    int slt  = (lg ^ ((lr >> 1) & 3)) * 8;

    const unsigned short* gaA[2];
    const unsigned short* gaB0;
    const unsigned short* actE = act + (size_t)e * CAP2 * NI;
    const unsigned short* dwnE = dwnT + (size_t)e * HDIM * NI;
#pragma unroll
    for (int i = 0; i < 2; ++i) {
        int arow = row0 + w * 32 + i * 16 + srow;
        gaA[i] = actE + (size_t)arow * NI + scol;
    }
    {
        int brow = n0 + w * 16 + srow;
        gaB0 = dwnE + (size_t)brow * NI + scol;
    }

    f32x4 acc[4][4];
#pragma unroll
    for (int m = 0; m < 4; ++m)
#pragma unroll
        for (int n = 0; n < 4; ++n) acc[m][n] = (f32x4){0.f, 0.f, 0.f, 0.f};

    STAGE_TILE(0, 0)
    STAGE_TILE(1, 1)
    KLOOP_BODY(NI / 32)

    unsigned short* yB = y + (size_t)(base_e + row0) * HDIM;
#pragma unroll
    for (int n = 0; n < 4; ++n) {
        int hc = n0 + wc * 64 + n * 16 + lr;
        float db = dwb[e * HDIM + hc];
#pragma unroll
        for (int m = 0; m < 4; ++m) {
#pragma unroll
            for (int r = 0; r < 4; ++r) {
                int rl = wr * 64 + m * 16 + lg * 4 + r;
                if (row0 + rl < cnt)
                    yB[(size_t)rl * HDIM + hc] = f2bf(rwgt[rl] * (acc[m][n][r] + db));
            }
        }
    }
}

// ------- out combine: out[t] = y[slot0] + y[slot1]; bf16 reads, coalesced, no atomics -------
__global__ __launch_bounds__(256) void out_combine_kernel(
    const unsigned short* __restrict__ y, const unsigned short* __restrict__ inv,
    const int* __restrict__ counts, float* __restrict__ out)
{
    __shared__ int sbase[NE];
    int tid = threadIdx.x;
    int t = blockIdx.x;
    if (tid == 0) {
        int s = 0;
#pragma unroll
        for (int e = 0; e < NE; ++e) { sbase[e] = s; s += counts[e]; }
    }
    __syncthreads();
    unsigned short v0 = inv[2 * t], v1 = inv[2 * t + 1];
    int s0 = sbase[v0 >> 11] + (v0 & 2047);
    int s1 = sbase[v1 >> 11] + (v1 & 2047);
    short4v a = *(const short4v*)(y + (size_t)s0 * HDIM + tid * 4);
    short4v c = *(const short4v*)(y + (size_t)s1 * HDIM + tid * 4);
    float4 o;
    o.x = bf2f((unsigned short)a[0]) + bf2f((unsigned short)c[0]);
    o.y = bf2f((unsigned short)a[1]) + bf2f((unsigned short)c[1]);
    o.z = bf2f((unsigned short)a[2]) + bf2f((unsigned short)c[2]);
    o.w = bf2f((unsigned short)a[3]) + bf2f((unsigned short)c[3]);
    *(float4*)(out + (size_t)t * HDIM + tid * 4) = o;
}

// ================= fallback path kernels (round-1 style, small ws) =================
__global__ __launch_bounds__(256) void router_kernel(
    const float* __restrict__ x, const float* __restrict__ rw,
    int* __restrict__ counts, int* __restrict__ toks, float* __restrict__ wgts)
{
    int gwave = (int)((blockIdx.x * 256 + threadIdx.x) >> 6);
    int lane = threadIdx.x & 63;
    if (gwave >= TOK) return;
    const float* xr = x + (size_t)gwave * HDIM;
    double acc[NE];
#pragma unroll
    for (int e = 0; e < NE; ++e) acc[e] = 0.0;
    for (int i = 0; i < HDIM / 64; ++i) {
        int h = i * 64 + lane;
        double xv = (double)xr[h];
        const float* r = rw + (size_t)h * NE;
#pragma unroll
        for (int e = 0; e < NE; ++e) acc[e] += xv * (double)r[e];
    }
#pragma unroll
    for (int e = 0; e < NE; ++e) {
        double v = acc[e];
#pragma unroll
        for (int off = 32; off > 0; off >>= 1) v += __shfl_xor(v, off);
        acc[e] = v;
    }
    if (lane == 0) {
        int i0 = 0; double v0 = acc[0];
#pragma unroll
        for (int e = 1; e < NE; ++e) if (acc[e] > v0) { v0 = acc[e]; i0 = e; }
        int i1 = -1; double v1 = -1e300;
#pragma unroll
        for (int e = 0; e < NE; ++e) if (e != i0 && acc[e] > v1) { v1 = acc[e]; i1 = e; }
        double e1 = exp(v1 - v0);
        float w0 = (float)(1.0 / (1.0 + e1));
        float w1 = (float)(e1 / (1.0 + e1));
        int p0 = atomicAdd(&counts[i0], 1);
        toks[i0 * CAP + p0] = gwave; wgts[i0 * CAP + p0] = w0;
        int p1 = atomicAdd(&counts[i1], 1);
        toks[i1 * CAP + p1] = gwave; wgts[i1 * CAP + p1] = w1;
    }
}

__global__ __launch_bounds__(256) void moe_kernel(
    const float* __restrict__ x,
    const float* __restrict__ gup, const float* __restrict__ gub,
    const float* __restrict__ dwn, const float* __restrict__ dwb,
    const int* __restrict__ counts, const int* __restrict__ toks,
    const float* __restrict__ wgts, float* __restrict__ out)
{
    int e = blockIdx.y;
    int cnt = counts[e];
    int row0 = blockIdx.x * 64;
    if (row0 >= cnt) return;

    __shared__ __align__(16) unsigned short sA[64][40];
    __shared__ __align__(16) unsigned short sB[64][40];
    __shared__ __align__(16) unsigned short sAct[64][520];
    __shared__ int   rtok[64];
    __shared__ float rwgt[64];

    int tid = threadIdx.x;
    if (tid < 64) {
        int idx = row0 + tid;
        bool v = idx < cnt;
        rtok[tid] = v ? toks[e * CAP + idx] : -1;
        rwgt[tid] = v ? wgts[e * CAP + idx] : 0.0f;
    }
    __syncthreads();

    int lane = tid & 63;
    int w = tid >> 6;
    int wr = w >> 1, wc = w & 1;
    int lr = lane & 15, lg = lane >> 4;
    int ar = tid >> 2, ac0 = (tid & 3) * 8;
    int bk = tid >> 3, bf0 = (tid & 7) * 8;
    const float* gupE = gup + (size_t)e * HDIM * F2;

    for (int nb = 0; nb < F2 / 64; ++nb) {
        f32x4 acc[2][2];
#pragma unroll
        for (int mi = 0; mi < 2; ++mi)
#pragma unroll
            for (int ni = 0; ni < 2; ++ni) acc[mi][ni] = (f32x4){0.f, 0.f, 0.f, 0.f};
        for (int kb = 0; kb < HDIM / 32; ++kb) {
            __syncthreads();
            {
                int tk = rtok[ar];
                short8 vv = {0,0,0,0,0,0,0,0};
                if (tk >= 0) {
                    const float* p = x + (size_t)tk * HDIM + kb * 32 + ac0;
                    float4 u0 = *(const float4*)(p); float4 u1 = *(const float4*)(p + 4);
                    vv[0]=(short)f2bf(u0.x); vv[1]=(short)f2bf(u0.y); vv[2]=(short)f2bf(u0.z); vv[3]=(short)f2bf(u0.w);
                    vv[4]=(short)f2bf(u1.x); vv[5]=(short)f2bf(u1.y); vv[6]=(short)f2bf(u1.z); vv[7]=(short)f2bf(u1.w);
                }
                *(short8*)&sA[ar][ac0] = vv;
            }
            {
                const float* p = gupE + (size_t)(kb * 32 + bk) * F2 + nb * 64 + bf0;
                float4 u0 = *(const float4*)(p); float4 u1 = *(const float4*)(p + 4);
                sB[bf0+0][bk]=f2bf(u0.x); sB[bf0+1][bk]=f2bf(u0.y); sB[bf0+2][bk]=f2bf(u0.z); sB[bf0+3][bk]=f2bf(u0.w);
                sB[bf0+4][bk]=f2bf(u1.x); sB[bf0+5][bk]=f2bf(u1.y); sB[bf0+6][bk]=f2bf(u1.z); sB[bf0+7][bk]=f2bf(u1.w);
            }
            __syncthreads();
            short8 a0 = *(const short8*)&sA[wr*32+lr][lg*8];
            short8 a1 = *(const short8*)&sA[wr*32+16+lr][lg*8];
            short8 b0 = *(const short8*)&sB[wc*32+lr][lg*8];
            short8 b1 = *(const short8*)&sB[wc*32+16+lr][lg*8];
            acc[0][0] = __builtin_amdgcn_mfma_f32_16x16x32_bf16(a0,b0,acc[0][0],0,0,0);
            acc[0][1] = __builtin_amdgcn_mfma_f32_16x16x32_bf16(a0,b1,acc[0][1],0,0,0);
            acc[1][0] = __builtin_amdgcn_mfma_f32_16x16x32_bf16(a1,b0,acc[1][0],0,0,0);
            acc[1][1] = __builtin_amdgcn_mfma_f32_16x16x32_bf16(a1,b1,acc[1][1],0,0,0);
        }
#pragma unroll
        for (int ni = 0; ni < 2; ++ni) {
            int fc = nb * 64 + wc * 32 + ni * 16 + lr;
            float bias = gub[e * F2 + fc];
#pragma unroll
            for (int mi = 0; mi < 2; ++mi)
#pragma unroll
                for (int r = 0; r < 4; ++r) {
                    float gu = acc[mi][ni][r] + bias;
                    float other = __shfl_xor(gu, 1);
                    float gate = (lr & 1) ? other : gu;
                    float up   = (lr & 1) ? gu : other;
                    gate = fminf(gate, LIMIT);
                    up = fminf(fmaxf(up, -LIMIT), LIMIT);
                    float glu = gate / (1.0f + __expf(-ALPHA * gate));
                    float av = (up + 1.0f) * glu;
                    if (!(lr & 1)) sAct[wr*32+mi*16+lg*4+r][fc >> 1] = f2bf(av);
                }
        }
    }
    __syncthreads();

    const float* dwnE = dwn + (size_t)e * NI * HDIM;
    int tks[2][4]; float wvs[2][4];
#pragma unroll
    for (int mi = 0; mi < 2; ++mi)
#pragma unroll
        for (int r = 0; r < 4; ++r) {
            int row = wr*32 + mi*16 + lg*4 + r;
            tks[mi][r] = rtok[row]; wvs[mi][r] = rwgt[row];
        }
    for (int nb = 0; nb < HDIM / 64; ++nb) {
        f32x4 acc[2][2];
#pragma unroll
        for (int mi = 0; mi < 2; ++mi)
#pragma unroll
            for (int ni = 0; ni < 2; ++ni) acc[mi][ni] = (f32x4){0.f,0.f,0.f,0.f};
        for (int kb = 0; kb < NI / 32; ++kb) {
            __syncthreads();
            {
                const float* p = dwnE + (size_t)(kb*32 + bk) * HDIM + nb*64 + bf0;
                float4 u0 = *(const float4*)(p); float4 u1 = *(const float4*)(p + 4);
                sB[bf0+0][bk]=f2bf(u0.x); sB[bf0+1][bk]=f2bf(u0.y); sB[bf0+2][bk]=f2bf(u0.z); sB[bf0+3][bk]=f2bf(u0.w);
                sB[bf0+4][bk]=f2bf(u1.x); sB[bf0+5][bk]=f2bf(u1.y); sB[bf0+6][bk]=f2bf(u1.z); sB[bf0+7][bk]=f2bf(u1.w);
            }
            __syncthreads();
            short8 a0 = *(const short8*)&sAct[wr*32+lr][kb*32+lg*8];
            short8 a1 = *(const short8*)&sAct[wr*32+16+lr][kb*32+lg*8];
            short8 b0 = *(const short8*)&sB[wc*32+lr][lg*8];
            short8 b1 = *(const short8*)&sB[wc*32+16+lr][lg*8];
            acc[0][0] = __builtin_amdgcn_mfma_f32_16x16x32_bf16(a0,b0,acc[0][0],0,0,0);
            acc[0][1] = __builtin_amdgcn_mfma_f32_16x16x32_bf16(a0,b1,acc[0][1],0,0,0);
            acc[1][0] = __builtin_amdgcn_mfma_f32_16x16x32_bf16(a1,b0,acc[1][0],0,0,0);
            acc[1][1] = __builtin_amdgcn_mfma_f32_16x16x32_bf16(a1,b1,acc[1][1],0,0,0);
        }
#pragma unroll
        for (int ni = 0; ni < 2; ++ni) {
            int hc = nb*64 + wc*32 + ni*16 + lr;
            float db = dwb[e * HDIM + hc];
#pragma unroll
            for (int mi = 0; mi < 2; ++mi)
#pragma unroll
                for (int r = 0; r < 4; ++r) {
                    int tk = tks[mi][r];
                    if (tk >= 0)
                        atomicAdd(out + (size_t)tk * HDIM + hc, wvs[mi][r] * (acc[mi][ni][r] + db));
                }
        }
    }
}

extern "C" void kernel_launch(void* const* d_in, const int* in_sizes, int n_in,
                              void* d_out, int out_size, void* d_ws, size_t ws_size,
                              hipStream_t stream) {
    const float* x   = (const float*)d_in[0];
    const float* rw  = (const float*)d_in[1];
    const float* gup = (const float*)d_in[2];
    const float* gub = (const float*)d_in[3];
    const float* dwn = (const float*)d_in[4];
    const float* dwb = (const float*)d_in[5];
    float* out = (float*)d_out;

    // ---- ws layout ----
    const size_t OFF_COUNTS = 0;                                   // 256 B
    const size_t OFF_ZP     = 256;                                 // 4 KB zero page
    const size_t OFF_INV    = 4352;                                // 32 KB
    const size_t OFF_TOKS   = OFF_INV  + (size_t)TOK * 2 * 2;
    const size_t OFF_WGTS   = OFF_TOKS + (size_t)NE * CAP * 4;
    const size_t OFF_DWNT   = OFF_WGTS + (size_t)NE * CAP * 4;
    const size_t OFF_ACT    = OFF_DWNT + (size_t)NE * NI * HDIM * 2;   // part (4MB) aliases here
    const size_t OFF_XBF    = OFF_ACT  + (size_t)NE * CAP2 * NI * 2;
    const size_t OFF_GUPT   = OFF_XBF  + (size_t)TOK * HDIM * 2;
    const size_t REQ_B      = OFF_GUPT + (size_t)NE * HDIM * F2 * 2;
    const size_t OFF_Y      = OFF_XBF;                             // aliases xbf+gupT (dead after gemm1)
    const size_t REQ_A      = OFF_Y + (size_t)2 * TOK * HDIM * 2;  // 32 MB compact bf16 y

    if (ws_size >= REQ_B) {
        int*            counts = (int*)((char*)d_ws + OFF_COUNTS);
        unsigned short* zp     = (unsigned short*)((char*)d_ws + OFF_ZP);
        unsigned short* inv    = (unsigned short*)((char*)d_ws + OFF_INV);
        int*            toks   = (int*)((char*)d_ws + OFF_TOKS);
        float*          wgts   = (float*)((char*)d_ws + OFF_WGTS);
        unsigned short* dwnT   = (unsigned short*)((char*)d_ws + OFF_DWNT);
        unsigned short* act    = (unsigned short*)((char*)d_ws + OFF_ACT);
        double*         part   = (double*)((char*)d_ws + OFF_ACT);
        unsigned short* xbf    = (unsigned short*)((char*)d_ws + OFF_XBF);
        unsigned short* gupT   = (unsigned short*)((char*)d_ws + OFF_GUPT);
        unsigned short* y      = (unsigned short*)((char*)d_ws + OFF_Y);

        hipMemsetAsync(d_ws, 0, 4352, stream);   // counts + zero page

        dim3 tg1(F2 / 64, HDIM / 64, NE);
        transpose_kernel<<<tg1, 256, 0, stream>>>(gup, gupT, HDIM, F2, 1);   // gate/up permuted
        dim3 tg2(HDIM / 64, NI / 64, NE);
        transpose_kernel<<<tg2, 256, 0, stream>>>(dwn, dwnT, NI, HDIM, 0);

        router_partial_kernel<<<(TOK / 16) * 4, 64, 0, stream>>>(x, rw, part, xbf);
        router_combine_kernel<<<TOK / 256, 256, 0, stream>>>(part, counts, toks, wgts, inv);

        int g1 = NE * (F2 / 128) * (CAP2 / 256);     // 16*8*8 = 1024
        gemm1_kernel<<<g1, 512, 0, stream>>>(xbf, gupT, gub, counts, toks, act, zp);
        int g2 = NE * (HDIM / 128) * (CAP2 / 256);   // 1024

        if (ws_size >= REQ_A) {
            gemm2_y_kernel<<<g2, 512, 0, stream>>>(act, dwnT, dwb, counts, wgts, y);
            out_combine_kernel<<<TOK, 256, 0, stream>>>(y, inv, counts, out);
        } else {
            hipMemsetAsync(d_out, 0, (size_t)out_size * sizeof(float), stream);
            out_combine_kernel<<<TOK, 256, 0, stream>>>(y, inv, counts, out);
        }
    } else {
        // fallback: round-1 path (~1.1 MB of ws)
        int*   counts = (int*)d_ws;
        int*   toks   = (int*)((char*)d_ws + 64);
        float* wgts   = (float*)((char*)d_ws + 64 + (size_t)NE * CAP * sizeof(int));
        hipMemsetAsync(d_ws, 0, 64, stream);
        hipMemsetAsync(d_out, 0, (size_t)out_size * sizeof(float), stream);
        router_kernel<<<TOK / 4, 256, 0, stream>>>(x, rw, counts, toks, wgts);
        dim3 gm(TOK / 64, NE);
        moe_kernel<<<gm, 256, 0, stream>>>(x, gup, gub, dwn, dwb, counts, toks, wgts, out);
    }
}

// Round 10
// 166.494 us; speedup vs baseline: 1.0752x; 1.0752x over previous
//
#include <hip/hip_runtime.h>
#include <hip/hip_bf16.h>
#include <math.h>

#define TOK   8192
#define HDIM  1024
#define NE    16
#define NI    512
#define F2    1024
#define CAP   8192
#define CAP2  2048
#define ALPHA 1.702f
#define LIMIT 7.0f

typedef __attribute__((ext_vector_type(8))) short short8;
typedef __attribute__((ext_vector_type(4))) short short4v;
typedef __attribute__((ext_vector_type(4))) float f32x4;

static __device__ __forceinline__ unsigned short f2bf(float f) {
    unsigned int u = __float_as_uint(f);
    u += 0x7FFFu + ((u >> 16) & 1u);
    return (unsigned short)(u >> 16);
}
static __device__ __forceinline__ float bf2f(unsigned short u) {
    return __uint_as_float((unsigned int)u << 16);
}

#define GLD_LDS16(g, l) __builtin_amdgcn_global_load_lds(                     \
    (const __attribute__((address_space(1))) void*)(g),                       \
    (__attribute__((address_space(3))) void*)(l), 16, 0, 0)

// ================= fused prep: weight transposes + router partials, ONE dispatch =================
// blocks [0,4096):   gup [E][1024][1024] -> gupT [E][n(perm)][k] bf16
// blocks [4096,6144): dwn [E][512][1024] -> dwnT [E][n][k] bf16
// blocks [6144,6656): router partial logits (4 waves/block, per-wave LDS slice) + x->bf16

static __device__ __forceinline__ void do_transpose(
    const float* __restrict__ in, unsigned short* __restrict__ out,
    int R, int C, int perm, int e, int bx, int by, char* smem, int tid)
{
    float (*t2)[65] = (float (*)[65])smem;
    const float* pin = in + (size_t)e * R * C;
    unsigned short* pout = out + (size_t)e * R * C;
    int c0 = bx * 64, r0 = by * 64;
#pragma unroll
    for (int j = 0; j < 4; ++j) {
        int idx4 = j * 256 + tid;
        int r = idx4 >> 4, c4 = (idx4 & 15) * 4;
        float4 v = *(const float4*)(pin + (size_t)(r0 + r) * C + c0 + c4);
        t2[c4 + 0][r] = v.x;
        t2[c4 + 1][r] = v.y;
        t2[c4 + 2][r] = v.z;
        t2[c4 + 3][r] = v.w;
    }
    __syncthreads();
#pragma unroll
    for (int j = 0; j < 2; ++j) {
        int idx = j * 256 + tid;
        int n = idx >> 3, k0 = (idx & 7) * 8;
        short8 v;
#pragma unroll
        for (int q = 0; q < 8; ++q) v[q] = (short)f2bf(t2[n][k0 + q]);
        int c = c0 + n;
        int orow;
        if (perm) {
            int tile = c >> 7, ct = c & 127;
            int fl = ct >> 1, h = ct & 1;
            orow = (tile << 7) | ((fl >> 4) << 5) | (h << 4) | (fl & 15);
        } else {
            orow = c;
        }
        *(short8*)(pout + (size_t)orow * R + r0 + k0) = v;
    }
}

__global__ __launch_bounds__(256) void prep_kernel(
    const float* __restrict__ x, const float* __restrict__ rw,
    const float* __restrict__ gup, const float* __restrict__ dwn,
    double* __restrict__ part, unsigned short* __restrict__ xbf,
    unsigned short* __restrict__ gupT, unsigned short* __restrict__ dwnT)
{
    __shared__ __align__(16) char smem[33792];
    int bid = blockIdx.x;
    int tid = threadIdx.x;

    if (bid < 4096) {
        // gup transpose (R=HDIM=1024, C=F2=1024, perm=1)
        do_transpose(gup, gupT, HDIM, F2, 1, bid >> 8, bid & 15, (bid >> 4) & 15, smem, tid);
        return;
    }
    if (bid < 6144) {
        // dwn transpose (R=NI=512, C=HDIM=1024, perm=0)
        int i = bid - 4096;
        do_transpose(dwn, dwnT, NI, HDIM, 0, i >> 7, i & 15, (i >> 4) & 7, smem, tid);
        return;
    }

    // ---- router partials: 512 blocks x 4 waves; wave w handles (tile=idx, ksl=w) ----
    int idx = bid - 6144;                 // 0..511 -> token tile (16 tokens)
    int w = tid >> 6;                     // ksl
    int lane = tid & 63;
    int tt = lane & 15, eg = lane >> 4;
    int t0 = idx * 16;
    int hbase = w * 256;

    float* sx  = (float*)(smem + w * 8448);           // [16][68]
    float* srw = (float*)(smem + w * 8448 + 4352);    // [64][16]

    double acc[4] = {0.0, 0.0, 0.0, 0.0};

    for (int hc = 0; hc < 4; ++hc) {
        int h0 = hbase + hc * 64;
        __syncthreads();
#pragma unroll
        for (int j = 0; j < 4; ++j) {
            int fidx = j * 64 + lane;
            int t = fidx >> 4, c4 = (fidx & 15) * 4;
            float4 v = *(const float4*)(x + (size_t)(t0 + t) * HDIM + h0 + c4);
            *(float4*)&sx[t * 68 + c4] = v;
            short4v s;
            s[0] = (short)f2bf(v.x); s[1] = (short)f2bf(v.y);
            s[2] = (short)f2bf(v.z); s[3] = (short)f2bf(v.w);
            *(short4v*)(xbf + (size_t)(t0 + t) * HDIM + h0 + c4) = s;
        }
#pragma unroll
        for (int j = 0; j < 4; ++j) {
            int ridx = j * 64 + lane;
            int h = ridx >> 2, e4 = (ridx & 3) * 4;
            float4 v = *(const float4*)(rw + (size_t)(h0 + h) * NE + e4);
            *(float4*)&srw[h * 16 + e4] = v;
        }
        __syncthreads();
#pragma unroll 8
        for (int j = 0; j < 64; ++j) {
            float xv = sx[tt * 68 + j];
            float4 wv = *(const float4*)&srw[j * 16 + eg * 4];
            double xd = (double)xv;
            acc[0] += xd * (double)wv.x;
            acc[1] += xd * (double)wv.y;
            acc[2] += xd * (double)wv.z;
            acc[3] += xd * (double)wv.w;
        }
    }
#pragma unroll
    for (int q = 0; q < 4; ++q)
        part[(size_t)(w * NE + eg * 4 + q) * TOK + t0 + tt] = acc[q];
}

// ===== router phase B: combine, top-2, softmax, aggregated scatter + inverse map =====
__global__ __launch_bounds__(256) void router_combine_kernel(
    const double* __restrict__ part,
    int* __restrict__ counts, int* __restrict__ toks, float* __restrict__ wgts,
    unsigned short* __restrict__ inv)
{
    __shared__ int lhist[NE];
    __shared__ int lbase[NE];
    int tid = threadIdx.x;
    int t = blockIdx.x * 256 + tid;
    if (tid < NE) lhist[tid] = 0;
    __syncthreads();

    double acc[NE];
#pragma unroll
    for (int e = 0; e < NE; ++e)
        acc[e] = part[(size_t)(0 * NE + e) * TOK + t]
               + part[(size_t)(1 * NE + e) * TOK + t]
               + part[(size_t)(2 * NE + e) * TOK + t]
               + part[(size_t)(3 * NE + e) * TOK + t];

    int i0 = 0; double v0 = acc[0];
#pragma unroll
    for (int e = 1; e < NE; ++e) if (acc[e] > v0) { v0 = acc[e]; i0 = e; }
    int i1 = -1; double v1 = -1e300;
#pragma unroll
    for (int e = 0; e < NE; ++e) if (e != i0 && acc[e] > v1) { v1 = acc[e]; i1 = e; }
    double e1 = exp(v1 - v0);
    float w0 = (float)(1.0 / (1.0 + e1));
    float w1 = (float)(e1 / (1.0 + e1));

    int r0 = atomicAdd(&lhist[i0], 1);
    int r1 = atomicAdd(&lhist[i1], 1);
    __syncthreads();
    if (tid < NE) lbase[tid] = atomicAdd(&counts[tid], lhist[tid]);
    __syncthreads();
    int p0 = lbase[i0] + r0; if (p0 > 2047) p0 = 2047;
    int p1 = lbase[i1] + r1; if (p1 > 2047) p1 = 2047;
    toks[i0 * CAP + p0] = t; wgts[i0 * CAP + p0] = w0;
    toks[i1 * CAP + p1] = t; wgts[i1 * CAP + p1] = w1;
    inv[2 * t]     = (unsigned short)((i0 << 11) | p0);
    inv[2 * t + 1] = (unsigned short)((i1 << 11) | p1);
}

// ===== 3-buffer counted-vmcnt K-loop (T3/T4, prefetch depth 2) — R8-verified =====
#define KLOOP_BODY(NT, KOFF)                                                          \
    int c0 = 0;                                                                       \
    for (int kb = 0; kb < (NT); ++kb) {                                               \
        if (kb + 2 < (NT)) {                                                          \
            int cpre = c0 + 2; if (cpre >= 3) cpre -= 3;                              \
            _Pragma("unroll")                                                         \
            for (int i = 0; i < 2; ++i) {                                             \
                GLD_LDS16(gaA[i] + (kb + 2) * (KOFF), &As[cpre][w * 32 + i * 16][0]); \
                GLD_LDS16(gaB[i] + (kb + 2) * (KOFF), &Bs[cpre][w * 32 + i * 16][0]); \
            }                                                                         \
            asm volatile("s_waitcnt vmcnt(8)" ::: "memory");                          \
        } else if (kb + 1 < (NT)) {                                                   \
            asm volatile("s_waitcnt vmcnt(4)" ::: "memory");                          \
        } else {                                                                      \
            asm volatile("s_waitcnt vmcnt(0)" ::: "memory");                          \
        }                                                                             \
        __builtin_amdgcn_sched_barrier(0);                                            \
        __builtin_amdgcn_s_barrier();                                                 \
        __builtin_amdgcn_sched_barrier(0);                                            \
        short8 af[4], bfr[4];                                                         \
        _Pragma("unroll")                                                             \
        for (int m = 0; m < 4; ++m) af[m] = *(const short8*)&As[c0][wr * 64 + m * 16 + lr][slt]; \
        _Pragma("unroll")                                                             \
        for (int n = 0; n < 4; ++n) bfr[n] = *(const short8*)&Bs[c0][wc * 64 + n * 16 + lr][slt]; \
        _Pragma("unroll")                                                             \
        for (int m = 0; m < 4; ++m)                                                   \
            _Pragma("unroll")                                                         \
            for (int n = 0; n < 4; ++n)                                               \
                acc[m][n] = __builtin_amdgcn_mfma_f32_16x16x32_bf16(af[m], bfr[n], acc[m][n], 0, 0, 0); \
        asm volatile("s_waitcnt lgkmcnt(0)" ::: "memory");                            \
        __builtin_amdgcn_sched_barrier(0);                                            \
        __builtin_amdgcn_s_barrier();                                                 \
        __builtin_amdgcn_sched_barrier(0);                                            \
        c0 = (c0 + 1 == 3) ? 0 : c0 + 1;                                              \
    }

#define KLOOP_PROLOGUE(KOFF)                                                          \
    _Pragma("unroll")                                                                 \
    for (int i = 0; i < 2; ++i) {                                                     \
        GLD_LDS16(gaA[i], &As[0][w * 32 + i * 16][0]);                                \
        GLD_LDS16(gaB[i], &Bs[0][w * 32 + i * 16][0]);                                \
    }                                                                                 \
    _Pragma("unroll")                                                                 \
    for (int i = 0; i < 2; ++i) {                                                     \
        GLD_LDS16(gaA[i] + (KOFF), &As[1][w * 32 + i * 16][0]);                       \
        GLD_LDS16(gaB[i] + (KOFF), &Bs[1][w * 32 + i * 16][0]);                       \
    }

// ---------------- GEMM1: x_bf (gathered) @ gupT^T + bias -> act (bf16) ----------------
__global__ __launch_bounds__(256) void gemm1_kernel(
    const unsigned short* __restrict__ xb, const unsigned short* __restrict__ gupT,
    const float* __restrict__ gub,
    const int* __restrict__ counts, const int* __restrict__ toks,
    unsigned short* __restrict__ act, const unsigned short* __restrict__ zp)
{
    int b = blockIdx.x;
    int e = b & 15;
    int j = b >> 4;
    int nt = j & 7;
    int mt = j >> 3;
    int cnt = counts[e];
    int row0 = mt * 128;
    if (row0 >= cnt) return;
    int n0 = nt * 128;

    __shared__ __align__(16) unsigned short As[3][128][32];
    __shared__ __align__(16) unsigned short Bs[3][128][32];
    __shared__ int rtok[128];

    int tid = threadIdx.x;
    int lane = tid & 63;
    int w = tid >> 6;
    int wr = w >> 1, wc = w & 1;
    int lr = lane & 15, lg = lane >> 4;

    if (tid < 128) {
        int p = row0 + tid;
        rtok[tid] = (p < cnt) ? toks[e * CAP + p] : -1;
    }
    __syncthreads();

    int srow = lane >> 2;
    int scol = (((lane & 3) ^ ((lane >> 3) & 3)) * 8);
    int slt = (lg ^ ((lr >> 1) & 3)) * 8;

    const unsigned short* gaA[2];
    const unsigned short* gaB[2];
    const unsigned short* gupE = gupT + (size_t)e * HDIM * F2;
#pragma unroll
    for (int i = 0; i < 2; ++i) {
        int arow = w * 32 + i * 16 + srow;
        int tk = rtok[arow];
        gaA[i] = (tk >= 0) ? (xb + (size_t)tk * HDIM + scol) : (zp + scol);
        int brow = n0 + w * 32 + i * 16 + srow;
        gaB[i] = gupE + (size_t)brow * HDIM + scol;
    }

    f32x4 acc[4][4];
#pragma unroll
    for (int m = 0; m < 4; ++m)
#pragma unroll
        for (int n = 0; n < 4; ++n) acc[m][n] = (f32x4){0.f, 0.f, 0.f, 0.f};

    KLOOP_PROLOGUE(32)
    KLOOP_BODY(HDIM / 32, 32)

    // epilogue: permuted B rows => acc[m][2q]=gate, acc[m][2q+1]=up of SAME feature, same lane
    unsigned short* actE = act + (size_t)e * CAP2 * NI;
    int fbase = nt * 64 + wc * 32;
#pragma unroll
    for (int q = 0; q < 2; ++q) {
        int f = fbase + q * 16 + lr;
        float bg = gub[e * F2 + 2 * f];
        float bu = gub[e * F2 + 2 * f + 1];
#pragma unroll
        for (int m = 0; m < 4; ++m) {
#pragma unroll
            for (int r = 0; r < 4; ++r) {
                float gate = acc[m][2 * q][r] + bg;
                float up   = acc[m][2 * q + 1][r] + bu;
                gate = fminf(gate, LIMIT);
                up   = fminf(fmaxf(up, -LIMIT), LIMIT);
                float glu = gate / (1.0f + __expf(-ALPHA * gate));
                float av  = (up + 1.0f) * glu;
                int row = row0 + wr * 64 + m * 16 + lg * 4 + r;
                actE[(size_t)row * NI + f] = f2bf(av);
            }
        }
    }
}

// ------- GEMM2 (tier A): act @ dwnT^T, *score, +bias -> compact bf16 y[base[e]+p][HDIM] -------
__global__ __launch_bounds__(256) void gemm2_y_kernel(
    const unsigned short* __restrict__ act, const unsigned short* __restrict__ dwnT,
    const float* __restrict__ dwb,
    const int* __restrict__ counts, const float* __restrict__ wgts,
    unsigned short* __restrict__ y)
{
    int b = blockIdx.x;
    int e = b & 15;
    int j = b >> 4;
    int nt = j & 7;
    int mt = j >> 3;
    int cnt = counts[e];
    int row0 = mt * 128;
    if (row0 >= cnt) return;
    int n0 = nt * 128;

    int base_e = 0;
#pragma unroll
    for (int q = 0; q < NE; ++q) base_e += (q < e) ? counts[q] : 0;

    __shared__ __align__(16) unsigned short As[3][128][32];
    __shared__ __align__(16) unsigned short Bs[3][128][32];
    __shared__ float rwgt[128];

    int tid = threadIdx.x;
    int lane = tid & 63;
    int w = tid >> 6;
    int wr = w >> 1, wc = w & 1;
    int lr = lane & 15, lg = lane >> 4;

    if (tid < 128) {
        int p = row0 + tid;
        rwgt[tid] = (p < cnt) ? wgts[e * CAP + p] : 0.0f;
    }
    __syncthreads();

    int srow = lane >> 2;
    int scol = (((lane & 3) ^ ((lane >> 3) & 3)) * 8);
    int slt = (lg ^ ((lr >> 1) & 3)) * 8;

    const unsigned short* gaA[2];
    const unsigned short* gaB[2];
    const unsigned short* actE = act + (size_t)e * CAP2 * NI;
    const unsigned short* dwnE = dwnT + (size_t)e * HDIM * NI;
#pragma unroll
    for (int i = 0; i < 2; ++i) {
        int arow = row0 + w * 32 + i * 16 + srow;
        gaA[i] = actE + (size_t)arow * NI + scol;
        int brow = n0 + w * 32 + i * 16 + srow;
        gaB[i] = dwnE + (size_t)brow * NI + scol;
    }

    f32x4 acc[4][4];
#pragma unroll
    for (int m = 0; m < 4; ++m)
#pragma unroll
        for (int n = 0; n < 4; ++n) acc[m][n] = (f32x4){0.f, 0.f, 0.f, 0.f};

    KLOOP_PROLOGUE(32)
    KLOOP_BODY(NI / 32, 32)

    unsigned short* yB = y + (size_t)(base_e + row0) * HDIM;
#pragma unroll
    for (int n = 0; n < 4; ++n) {
        int hc = n0 + wc * 64 + n * 16 + lr;
        float db = dwb[e * HDIM + hc];
#pragma unroll
        for (int m = 0; m < 4; ++m) {
#pragma unroll
            for (int r = 0; r < 4; ++r) {
                int rl = wr * 64 + m * 16 + lg * 4 + r;
                if (row0 + rl < cnt)
                    yB[(size_t)rl * HDIM + hc] = f2bf(rwgt[rl] * (acc[m][n][r] + db));
            }
        }
    }
}

// ------- out combine: out[t] = y[slot0] + y[slot1]; bf16 reads, coalesced, no atomics -------
__global__ __launch_bounds__(256) void out_combine_kernel(
    const unsigned short* __restrict__ y, const unsigned short* __restrict__ inv,
    const int* __restrict__ counts, float* __restrict__ out)
{
    __shared__ int sbase[NE];
    int tid = threadIdx.x;
    int t = blockIdx.x;
    if (tid == 0) {
        int s = 0;
#pragma unroll
        for (int e = 0; e < NE; ++e) { sbase[e] = s; s += counts[e]; }
    }
    __syncthreads();
    unsigned short v0 = inv[2 * t], v1 = inv[2 * t + 1];
    int s0 = sbase[v0 >> 11] + (v0 & 2047);
    int s1 = sbase[v1 >> 11] + (v1 & 2047);
    short4v a = *(const short4v*)(y + (size_t)s0 * HDIM + tid * 4);
    short4v c = *(const short4v*)(y + (size_t)s1 * HDIM + tid * 4);
    float4 o;
    o.x = bf2f((unsigned short)a[0]) + bf2f((unsigned short)c[0]);
    o.y = bf2f((unsigned short)a[1]) + bf2f((unsigned short)c[1]);
    o.z = bf2f((unsigned short)a[2]) + bf2f((unsigned short)c[2]);
    o.w = bf2f((unsigned short)a[3]) + bf2f((unsigned short)c[3]);
    *(float4*)(out + (size_t)t * HDIM + tid * 4) = o;
}

// ================= fallback path kernels (round-1 style, small ws) =================
__global__ __launch_bounds__(256) void router_kernel(
    const float* __restrict__ x, const float* __restrict__ rw,
    int* __restrict__ counts, int* __restrict__ toks, float* __restrict__ wgts)
{
    int gwave = (int)((blockIdx.x * 256 + threadIdx.x) >> 6);
    int lane = threadIdx.x & 63;
    if (gwave >= TOK) return;
    const float* xr = x + (size_t)gwave * HDIM;
    double acc[NE];
#pragma unroll
    for (int e = 0; e < NE; ++e) acc[e] = 0.0;
    for (int i = 0; i < HDIM / 64; ++i) {
        int h = i * 64 + lane;
        double xv = (double)xr[h];
        const float* r = rw + (size_t)h * NE;
#pragma unroll
        for (int e = 0; e < NE; ++e) acc[e] += xv * (double)r[e];
    }
#pragma unroll
    for (int e = 0; e < NE; ++e) {
        double v = acc[e];
#pragma unroll
        for (int off = 32; off > 0; off >>= 1) v += __shfl_xor(v, off);
        acc[e] = v;
    }
    if (lane == 0) {
        int i0 = 0; double v0 = acc[0];
#pragma unroll
        for (int e = 1; e < NE; ++e) if (acc[e] > v0) { v0 = acc[e]; i0 = e; }
        int i1 = -1; double v1 = -1e300;
#pragma unroll
        for (int e = 0; e < NE; ++e) if (e != i0 && acc[e] > v1) { v1 = acc[e]; i1 = e; }
        double e1 = exp(v1 - v0);
        float w0 = (float)(1.0 / (1.0 + e1));
        float w1 = (float)(e1 / (1.0 + e1));
        int p0 = atomicAdd(&counts[i0], 1);
        toks[i0 * CAP + p0] = gwave; wgts[i0 * CAP + p0] = w0;
        int p1 = atomicAdd(&counts[i1], 1);
        toks[i1 * CAP + p1] = gwave; wgts[i1 * CAP + p1] = w1;
    }
}

__global__ __launch_bounds__(256) void moe_kernel(
    const float* __restrict__ x,
    const float* __restrict__ gup, const float* __restrict__ gub,
    const float* __restrict__ dwn, const float* __restrict__ dwb,
    const int* __restrict__ counts, const int* __restrict__ toks,
    const float* __restrict__ wgts, float* __restrict__ out)
{
    int e = blockIdx.y;
    int cnt = counts[e];
    int row0 = blockIdx.x * 64;
    if (row0 >= cnt) return;

    __shared__ __align__(16) unsigned short sA[64][40];
    __shared__ __align__(16) unsigned short sB[64][40];
    __shared__ __align__(16) unsigned short sAct[64][520];
    __shared__ int   rtok[64];
    __shared__ float rwgt[64];

    int tid = threadIdx.x;
    if (tid < 64) {
        int idx = row0 + tid;
        bool v = idx < cnt;
        rtok[tid] = v ? toks[e * CAP + idx] : -1;
        rwgt[tid] = v ? wgts[e * CAP + idx] : 0.0f;
    }
    __syncthreads();

    int lane = tid & 63;
    int w = tid >> 6;
    int wr = w >> 1, wc = w & 1;
    int lr = lane & 15, lg = lane >> 4;
    int ar = tid >> 2, ac0 = (tid & 3) * 8;
    int bk = tid >> 3, bf0 = (tid & 7) * 8;
    const float* gupE = gup + (size_t)e * HDIM * F2;

    for (int nb = 0; nb < F2 / 64; ++nb) {
        f32x4 acc[2][2];
#pragma unroll
        for (int mi = 0; mi < 2; ++mi)
#pragma unroll
            for (int ni = 0; ni < 2; ++ni) acc[mi][ni] = (f32x4){0.f, 0.f, 0.f, 0.f};
        for (int kb = 0; kb < HDIM / 32; ++kb) {
            __syncthreads();
            {
                int tk = rtok[ar];
                short8 vv = {0,0,0,0,0,0,0,0};
                if (tk >= 0) {
                    const float* p = x + (size_t)tk * HDIM + kb * 32 + ac0;
                    float4 u0 = *(const float4*)(p); float4 u1 = *(const float4*)(p + 4);
                    vv[0]=(short)f2bf(u0.x); vv[1]=(short)f2bf(u0.y); vv[2]=(short)f2bf(u0.z); vv[3]=(short)f2bf(u0.w);
                    vv[4]=(short)f2bf(u1.x); vv[5]=(short)f2bf(u1.y); vv[6]=(short)f2bf(u1.z); vv[7]=(short)f2bf(u1.w);
                }
                *(short8*)&sA[ar][ac0] = vv;
            }
            {
                const float* p = gupE + (size_t)(kb * 32 + bk) * F2 + nb * 64 + bf0;
                float4 u0 = *(const float4*)(p); float4 u1 = *(const float4*)(p + 4);
                sB[bf0+0][bk]=f2bf(u0.x); sB[bf0+1][bk]=f2bf(u0.y); sB[bf0+2][bk]=f2bf(u0.z); sB[bf0+3][bk]=f2bf(u0.w);
                sB[bf0+4][bk]=f2bf(u1.x); sB[bf0+5][bk]=f2bf(u1.y); sB[bf0+6][bk]=f2bf(u1.z); sB[bf0+7][bk]=f2bf(u1.w);
            }
            __syncthreads();
            short8 a0 = *(const short8*)&sA[wr*32+lr][lg*8];
            short8 a1 = *(const short8*)&sA[wr*32+16+lr][lg*8];
            short8 b0 = *(const short8*)&sB[wc*32+lr][lg*8];
            short8 b1 = *(const short8*)&sB[wc*32+16+lr][lg*8];
            acc[0][0] = __builtin_amdgcn_mfma_f32_16x16x32_bf16(a0,b0,acc[0][0],0,0,0);
            acc[0][1] = __builtin_amdgcn_mfma_f32_16x16x32_bf16(a0,b1,acc[0][1],0,0,0);
            acc[1][0] = __builtin_amdgcn_mfma_f32_16x16x32_bf16(a1,b0,acc[1][0],0,0,0);
            acc[1][1] = __builtin_amdgcn_mfma_f32_16x16x32_bf16(a1,b1,acc[1][1],0,0,0);
        }
#pragma unroll
        for (int ni = 0; ni < 2; ++ni) {
            int fc = nb * 64 + wc * 32 + ni * 16 + lr;
            float bias = gub[e * F2 + fc];
#pragma unroll
            for (int mi = 0; mi < 2; ++mi)
#pragma unroll
                for (int r = 0; r < 4; ++r) {
                    float gu = acc[mi][ni][r] + bias;
                    float other = __shfl_xor(gu, 1);
                    float gate = (lr & 1) ? other : gu;
                    float up   = (lr & 1) ? gu : other;
                    gate = fminf(gate, LIMIT);
                    up = fminf(fmaxf(up, -LIMIT), LIMIT);
                    float glu = gate / (1.0f + __expf(-ALPHA * gate));
                    float av = (up + 1.0f) * glu;
                    if (!(lr & 1)) sAct[wr*32+mi*16+lg*4+r][fc >> 1] = f2bf(av);
                }
        }
    }
    __syncthreads();

    const float* dwnE = dwn + (size_t)e * NI * HDIM;
    int tks[2][4]; float wvs[2][4];
#pragma unroll
    for (int mi = 0; mi < 2; ++mi)
#pragma unroll
        for (int r = 0; r < 4; ++r) {
            int row = wr*32 + mi*16 + lg*4 + r;
            tks[mi][r] = rtok[row]; wvs[mi][r] = rwgt[row];
        }
    for (int nb = 0; nb < HDIM / 64; ++nb) {
        f32x4 acc[2][2];
#pragma unroll
        for (int mi = 0; mi < 2; ++mi)
#pragma unroll
            for (int ni = 0; ni < 2; ++ni) acc[mi][ni] = (f32x4){0.f,0.f,0.f,0.f};
        for (int kb = 0; kb < NI / 32; ++kb) {
            __syncthreads();
            {
                const float* p = dwnE + (size_t)(kb*32 + bk) * HDIM + nb*64 + bf0;
                float4 u0 = *(const float4*)(p); float4 u1 = *(const float4*)(p + 4);
                sB[bf0+0][bk]=f2bf(u0.x); sB[bf0+1][bk]=f2bf(u0.y); sB[bf0+2][bk]=f2bf(u0.z); sB[bf0+3][bk]=f2bf(u0.w);
                sB[bf0+4][bk]=f2bf(u1.x); sB[bf0+5][bk]=f2bf(u1.y); sB[bf0+6][bk]=f2bf(u1.z); sB[bf0+7][bk]=f2bf(u1.w);
            }
            __syncthreads();
            short8 a0 = *(const short8*)&sAct[wr*32+lr][kb*32+lg*8];
            short8 a1 = *(const short8*)&sAct[wr*32+16+lr][kb*32+lg*8];
            short8 b0 = *(const short8*)&sB[wc*32+lr][lg*8];
            short8 b1 = *(const short8*)&sB[wc*32+16+lr][lg*8];
            acc[0][0] = __builtin_amdgcn_mfma_f32_16x16x32_bf16(a0,b0,acc[0][0],0,0,0);
            acc[0][1] = __builtin_amdgcn_mfma_f32_16x16x32_bf16(a0,b1,acc[0][1],0,0,0);
            acc[1][0] = __builtin_amdgcn_mfma_f32_16x16x32_bf16(a1,b0,acc[1][0],0,0,0);
            acc[1][1] = __builtin_amdgcn_mfma_f32_16x16x32_bf16(a1,b1,acc[1][1],0,0,0);
        }
#pragma unroll
        for (int ni = 0; ni < 2; ++ni) {
            int hc = nb*64 + wc*32 + ni*16 + lr;
            float db = dwb[e * HDIM + hc];
#pragma unroll
            for (int mi = 0; mi < 2; ++mi)
#pragma unroll
                for (int r = 0; r < 4; ++r) {
                    int tk = tks[mi][r];
                    if (tk >= 0)
                        atomicAdd(out + (size_t)tk * HDIM + hc, wvs[mi][r] * (acc[mi][ni][r] + db));
                }
        }
    }
}

extern "C" void kernel_launch(void* const* d_in, const int* in_sizes, int n_in,
                              void* d_out, int out_size, void* d_ws, size_t ws_size,
                              hipStream_t stream) {
    const float* x   = (const float*)d_in[0];
    const float* rw  = (const float*)d_in[1];
    const float* gup = (const float*)d_in[2];
    const float* gub = (const float*)d_in[3];
    const float* dwn = (const float*)d_in[4];
    const float* dwb = (const float*)d_in[5];
    float* out = (float*)d_out;

    // ---- ws layout ----
    const size_t OFF_COUNTS = 0;                                   // 256 B
    const size_t OFF_ZP     = 256;                                 // 4 KB zero page
    const size_t OFF_INV    = 4352;                                // 32 KB
    const size_t OFF_TOKS   = OFF_INV  + (size_t)TOK * 2 * 2;
    const size_t OFF_WGTS   = OFF_TOKS + (size_t)NE * CAP * 4;
    const size_t OFF_DWNT   = OFF_WGTS + (size_t)NE * CAP * 4;
    const size_t OFF_ACT    = OFF_DWNT + (size_t)NE * NI * HDIM * 2;   // part (4MB) aliases here
    const size_t OFF_XBF    = OFF_ACT  + (size_t)NE * CAP2 * NI * 2;
    const size_t OFF_GUPT   = OFF_XBF  + (size_t)TOK * HDIM * 2;
    const size_t REQ_B      = OFF_GUPT + (size_t)NE * HDIM * F2 * 2;
    const size_t OFF_Y      = OFF_XBF;                             // aliases xbf+gupT (dead after gemm1)
    const size_t REQ_A      = OFF_Y + (size_t)2 * TOK * HDIM * 2;  // 32 MB compact bf16 y

    if (ws_size >= REQ_B) {
        int*            counts = (int*)((char*)d_ws + OFF_COUNTS);
        unsigned short* zp     = (unsigned short*)((char*)d_ws + OFF_ZP);
        unsigned short* inv    = (unsigned short*)((char*)d_ws + OFF_INV);
        int*            toks   = (int*)((char*)d_ws + OFF_TOKS);
        float*          wgts   = (float*)((char*)d_ws + OFF_WGTS);
        unsigned short* dwnT   = (unsigned short*)((char*)d_ws + OFF_DWNT);
        unsigned short* act    = (unsigned short*)((char*)d_ws + OFF_ACT);
        double*         part   = (double*)((char*)d_ws + OFF_ACT);
        unsigned short* xbf    = (unsigned short*)((char*)d_ws + OFF_XBF);
        unsigned short* gupT   = (unsigned short*)((char*)d_ws + OFF_GUPT);
        unsigned short* y      = (unsigned short*)((char*)d_ws + OFF_Y);

        hipMemsetAsync(d_ws, 0, 4352, stream);   // counts + zero page

        // fused prep: both weight transposes + router partials in one dispatch
        prep_kernel<<<4096 + 2048 + 512, 256, 0, stream>>>(
            x, rw, gup, dwn, part, xbf, gupT, dwnT);

        router_combine_kernel<<<TOK / 256, 256, 0, stream>>>(part, counts, toks, wgts, inv);

        int g1 = (CAP2 / 128) * (F2 / 128) * NE;     // 2048
        gemm1_kernel<<<g1, 256, 0, stream>>>(xbf, gupT, gub, counts, toks, act, zp);
        int g2 = (CAP2 / 128) * (HDIM / 128) * NE;   // 2048

        if (ws_size >= REQ_A) {
            gemm2_y_kernel<<<g2, 256, 0, stream>>>(act, dwnT, dwb, counts, wgts, y);
            out_combine_kernel<<<TOK, 256, 0, stream>>>(y, inv, counts, out);
        } else {
            hipMemsetAsync(d_out, 0, (size_t)out_size * sizeof(float), stream);
            out_combine_kernel<<<TOK, 256, 0, stream>>>(y, inv, counts, out);
        }
    } else {
        // fallback: round-1 path (~1.1 MB of ws)
        int*   counts = (int*)d_ws;
        int*   toks   = (int*)((char*)d_ws + 64);
        float* wgts   = (float*)((char*)d_ws + 64 + (size_t)NE * CAP * sizeof(int));
        hipMemsetAsync(d_ws, 0, 64, stream);
        hipMemsetAsync(d_out, 0, (size_t)out_size * sizeof(float), stream);
        router_kernel<<<TOK / 4, 256, 0, stream>>>(x, rw, counts, toks, wgts);
        dim3 gm(TOK / 64, NE);
        moe_kernel<<<gm, 256, 0, stream>>>(x, gup, gub, dwn, dwb, counts, toks, wgts, out);
    }
}

// Round 11
// 159.876 us; speedup vs baseline: 1.1197x; 1.0414x over previous
//
#include <hip/hip_runtime.h>
#include <hip/hip_bf16.h>
#include <math.h>

#define TOK   8192
#define HDIM  1024
#define NE    16
#define NI    512
#define F2    1024
#define CAP   8192
#define CAP2  2048
#define ALPHA 1.702f
#define LIMIT 7.0f

typedef __attribute__((ext_vector_type(8))) short short8;
typedef __attribute__((ext_vector_type(4))) short short4v;
typedef __attribute__((ext_vector_type(4))) float f32x4;

static __device__ __forceinline__ unsigned short f2bf(float f) {
    unsigned int u = __float_as_uint(f);
    u += 0x7FFFu + ((u >> 16) & 1u);
    return (unsigned short)(u >> 16);
}
static __device__ __forceinline__ float bf2f(unsigned short u) {
    return __uint_as_float((unsigned int)u << 16);
}

#define GLD_LDS16(g, l) __builtin_amdgcn_global_load_lds(                     \
    (const __attribute__((address_space(1))) void*)(g),                       \
    (__attribute__((address_space(3))) void*)(l), 16, 0, 0)

// ================= fused prep: router partials FIRST, then weight transposes =================
// blocks [0,512):    router partial logits (4 waves/block) + x->bf16
// blocks [512,1536): gup [E][1024][1024] -> gupT [E][n(perm)][k] bf16   (64n x 256k tiles)
// blocks [1536,2048): dwn [E][512][1024] -> dwnT [E][n][k] bf16         (64n x 256k tiles)

// 64n x 256k transpose tile: 512B-contiguous output runs per 32-lane group.
static __device__ __forceinline__ void do_transpose256(
    const float* __restrict__ in, unsigned short* __restrict__ out,
    int R, int C, int perm, int e, int bx, int by, char* smem, int tid)
{
    unsigned short (*t2)[264] = (unsigned short (*)[264])smem;   // [n][k], 33792 B
    const float* pin = in + (size_t)e * R * C;
    unsigned short* pout = out + (size_t)e * R * C;
    int c0 = bx * 64, r0 = by * 256;

    // read 256 k-rows x 64 n (row-pairs packed to dword LDS stores)
#pragma unroll
    for (int j = 0; j < 8; ++j) {
        int idx = j * 256 + tid;               // 2048 = 128 r-pairs x 16 c4-groups
        int rp = idx >> 4, c4 = (idx & 15) * 4;
        const float* p0 = pin + (size_t)(r0 + 2 * rp) * C + c0 + c4;
        float4 v0 = *(const float4*)(p0);
        float4 v1 = *(const float4*)(p0 + C);
        unsigned int u0 = (unsigned int)f2bf(v0.x) | ((unsigned int)f2bf(v1.x) << 16);
        unsigned int u1 = (unsigned int)f2bf(v0.y) | ((unsigned int)f2bf(v1.y) << 16);
        unsigned int u2 = (unsigned int)f2bf(v0.z) | ((unsigned int)f2bf(v1.z) << 16);
        unsigned int u3 = (unsigned int)f2bf(v0.w) | ((unsigned int)f2bf(v1.w) << 16);
        *(unsigned int*)&t2[c4 + 0][2 * rp] = u0;
        *(unsigned int*)&t2[c4 + 1][2 * rp] = u1;
        *(unsigned int*)&t2[c4 + 2][2 * rp] = u2;
        *(unsigned int*)&t2[c4 + 3][2 * rp] = u3;
    }
    __syncthreads();

    // write 64 n-rows x 256 k: 32 lanes x short8 = 512B contiguous per row
#pragma unroll
    for (int j = 0; j < 8; ++j) {
        int idx = j * 256 + tid;               // 2048 = 64 n x 32 chunks
        int n = idx >> 5, k0 = (idx & 31) * 8;
        short8 v = *(const short8*)&t2[n][k0];
        int c = c0 + n;
        int orow;
        if (perm) {
            int tile = c >> 7, ct = c & 127;
            int fl = ct >> 1, h = ct & 1;
            orow = (tile << 7) | ((fl >> 4) << 5) | (h << 4) | (fl & 15);
        } else {
            orow = c;
        }
        *(short8*)(pout + (size_t)orow * R + r0 + k0) = v;
    }
}

__global__ __launch_bounds__(256) void prep_kernel(
    const float* __restrict__ x, const float* __restrict__ rw,
    const float* __restrict__ gup, const float* __restrict__ dwn,
    double* __restrict__ part, unsigned short* __restrict__ xbf,
    unsigned short* __restrict__ gupT, unsigned short* __restrict__ dwnT)
{
    __shared__ __align__(16) char smem[33792];
    int bid = blockIdx.x;
    int tid = threadIdx.x;

    if (bid >= 512) {
        if (bid < 1536) {
            int i = bid - 512;                 // gup: e(16) x ktile(4) x ntile(16)
            do_transpose256(gup, gupT, HDIM, F2, 1, i >> 6, i & 15, (i >> 4) & 3, smem, tid);
        } else {
            int i = bid - 1536;                // dwn: e(16) x ktile(2) x ntile(16)
            do_transpose256(dwn, dwnT, NI, HDIM, 0, i >> 5, i & 15, (i >> 4) & 1, smem, tid);
        }
        return;
    }

    // ---- router partials: 512 blocks x 4 waves; wave w handles (tile=bid, ksl=w) ----
    int idx = bid;
    int w = tid >> 6;
    int lane = tid & 63;
    int tt = lane & 15, eg = lane >> 4;
    int t0 = idx * 16;
    int hbase = w * 256;

    float* sx  = (float*)(smem + w * 8448);           // [16][68]
    float* srw = (float*)(smem + w * 8448 + 4352);    // [64][16]

    double acc[4] = {0.0, 0.0, 0.0, 0.0};

    for (int hc = 0; hc < 4; ++hc) {
        int h0 = hbase + hc * 64;
        __syncthreads();
#pragma unroll
        for (int j = 0; j < 4; ++j) {
            int fidx = j * 64 + lane;
            int t = fidx >> 4, c4 = (fidx & 15) * 4;
            float4 v = *(const float4*)(x + (size_t)(t0 + t) * HDIM + h0 + c4);
            *(float4*)&sx[t * 68 + c4] = v;
            short4v s;
            s[0] = (short)f2bf(v.x); s[1] = (short)f2bf(v.y);
            s[2] = (short)f2bf(v.z); s[3] = (short)f2bf(v.w);
            *(short4v*)(xbf + (size_t)(t0 + t) * HDIM + h0 + c4) = s;
        }
#pragma unroll
        for (int j = 0; j < 4; ++j) {
            int ridx = j * 64 + lane;
            int h = ridx >> 2, e4 = (ridx & 3) * 4;
            float4 v = *(const float4*)(rw + (size_t)(h0 + h) * NE + e4);
            *(float4*)&srw[h * 16 + e4] = v;
        }
        __syncthreads();
#pragma unroll 8
        for (int j = 0; j < 64; ++j) {
            float xv = sx[tt * 68 + j];
            float4 wv = *(const float4*)&srw[j * 16 + eg * 4];
            double xd = (double)xv;
            acc[0] += xd * (double)wv.x;
            acc[1] += xd * (double)wv.y;
            acc[2] += xd * (double)wv.z;
            acc[3] += xd * (double)wv.w;
        }
    }
#pragma unroll
    for (int q = 0; q < 4; ++q)
        part[(size_t)(w * NE + eg * 4 + q) * TOK + t0 + tt] = acc[q];
}

// ===== router phase B: combine, top-2, softmax, aggregated scatter + inverse map =====
__global__ __launch_bounds__(256) void router_combine_kernel(
    const double* __restrict__ part,
    int* __restrict__ counts, int* __restrict__ toks, float* __restrict__ wgts,
    unsigned short* __restrict__ inv)
{
    __shared__ int lhist[NE];
    __shared__ int lbase[NE];
    int tid = threadIdx.x;
    int t = blockIdx.x * 256 + tid;
    if (tid < NE) lhist[tid] = 0;
    __syncthreads();

    double acc[NE];
#pragma unroll
    for (int e = 0; e < NE; ++e)
        acc[e] = part[(size_t)(0 * NE + e) * TOK + t]
               + part[(size_t)(1 * NE + e) * TOK + t]
               + part[(size_t)(2 * NE + e) * TOK + t]
               + part[(size_t)(3 * NE + e) * TOK + t];

    int i0 = 0; double v0 = acc[0];
#pragma unroll
    for (int e = 1; e < NE; ++e) if (acc[e] > v0) { v0 = acc[e]; i0 = e; }
    int i1 = -1; double v1 = -1e300;
#pragma unroll
    for (int e = 0; e < NE; ++e) if (e != i0 && acc[e] > v1) { v1 = acc[e]; i1 = e; }
    double e1 = exp(v1 - v0);
    float w0 = (float)(1.0 / (1.0 + e1));
    float w1 = (float)(e1 / (1.0 + e1));

    int r0 = atomicAdd(&lhist[i0], 1);
    int r1 = atomicAdd(&lhist[i1], 1);
    __syncthreads();
    if (tid < NE) lbase[tid] = atomicAdd(&counts[tid], lhist[tid]);
    __syncthreads();
    int p0 = lbase[i0] + r0; if (p0 > 2047) p0 = 2047;
    int p1 = lbase[i1] + r1; if (p1 > 2047) p1 = 2047;
    toks[i0 * CAP + p0] = t; wgts[i0 * CAP + p0] = w0;
    toks[i1 * CAP + p1] = t; wgts[i1 * CAP + p1] = w1;
    inv[2 * t]     = (unsigned short)((i0 << 11) | p0);
    inv[2 * t + 1] = (unsigned short)((i1 << 11) | p1);
}

// ===== 3-buffer counted-vmcnt K-loop (T3/T4, prefetch depth 2) — R8-verified =====
#define KLOOP_BODY(NT, KOFF)                                                          \
    int c0 = 0;                                                                       \
    for (int kb = 0; kb < (NT); ++kb) {                                               \
        if (kb + 2 < (NT)) {                                                          \
            int cpre = c0 + 2; if (cpre >= 3) cpre -= 3;                              \
            _Pragma("unroll")                                                         \
            for (int i = 0; i < 2; ++i) {                                             \
                GLD_LDS16(gaA[i] + (kb + 2) * (KOFF), &As[cpre][w * 32 + i * 16][0]); \
                GLD_LDS16(gaB[i] + (kb + 2) * (KOFF), &Bs[cpre][w * 32 + i * 16][0]); \
            }                                                                         \
            asm volatile("s_waitcnt vmcnt(8)" ::: "memory");                          \
        } else if (kb + 1 < (NT)) {                                                   \
            asm volatile("s_waitcnt vmcnt(4)" ::: "memory");                          \
        } else {                                                                      \
            asm volatile("s_waitcnt vmcnt(0)" ::: "memory");                          \
        }                                                                             \
        __builtin_amdgcn_sched_barrier(0);                                            \
        __builtin_amdgcn_s_barrier();                                                 \
        __builtin_amdgcn_sched_barrier(0);                                            \
        short8 af[4], bfr[4];                                                         \
        _Pragma("unroll")                                                             \
        for (int m = 0; m < 4; ++m) af[m] = *(const short8*)&As[c0][wr * 64 + m * 16 + lr][slt]; \
        _Pragma("unroll")                                                             \
        for (int n = 0; n < 4; ++n) bfr[n] = *(const short8*)&Bs[c0][wc * 64 + n * 16 + lr][slt]; \
        _Pragma("unroll")                                                             \
        for (int m = 0; m < 4; ++m)                                                   \
            _Pragma("unroll")                                                         \
            for (int n = 0; n < 4; ++n)                                               \
                acc[m][n] = __builtin_amdgcn_mfma_f32_16x16x32_bf16(af[m], bfr[n], acc[m][n], 0, 0, 0); \
        asm volatile("s_waitcnt lgkmcnt(0)" ::: "memory");                            \
        __builtin_amdgcn_sched_barrier(0);                                            \
        __builtin_amdgcn_s_barrier();                                                 \
        __builtin_amdgcn_sched_barrier(0);                                            \
        c0 = (c0 + 1 == 3) ? 0 : c0 + 1;                                              \
    }

#define KLOOP_PROLOGUE(KOFF)                                                          \
    _Pragma("unroll")                                                                 \
    for (int i = 0; i < 2; ++i) {                                                     \
        GLD_LDS16(gaA[i], &As[0][w * 32 + i * 16][0]);                                \
        GLD_LDS16(gaB[i], &Bs[0][w * 32 + i * 16][0]);                                \
    }                                                                                 \
    _Pragma("unroll")                                                                 \
    for (int i = 0; i < 2; ++i) {                                                     \
        GLD_LDS16(gaA[i] + (KOFF), &As[1][w * 32 + i * 16][0]);                       \
        GLD_LDS16(gaB[i] + (KOFF), &Bs[1][w * 32 + i * 16][0]);                       \
    }

// ---------------- GEMM1: x_bf (gathered) @ gupT^T + bias -> act (bf16) ----------------
__global__ __launch_bounds__(256) void gemm1_kernel(
    const unsigned short* __restrict__ xb, const unsigned short* __restrict__ gupT,
    const float* __restrict__ gub,
    const int* __restrict__ counts, const int* __restrict__ toks,
    unsigned short* __restrict__ act, const unsigned short* __restrict__ zp)
{
    int b = blockIdx.x;
    int e = b & 15;
    int j = b >> 4;
    int nt = j & 7;
    int mt = j >> 3;
    int cnt = counts[e];
    int row0 = mt * 128;
    if (row0 >= cnt) return;
    int n0 = nt * 128;

    __shared__ __align__(16) unsigned short As[3][128][32];
    __shared__ __align__(16) unsigned short Bs[3][128][32];
    __shared__ int rtok[128];

    int tid = threadIdx.x;
    int lane = tid & 63;
    int w = tid >> 6;
    int wr = w >> 1, wc = w & 1;
    int lr = lane & 15, lg = lane >> 4;

    if (tid < 128) {
        int p = row0 + tid;
        rtok[tid] = (p < cnt) ? toks[e * CAP + p] : -1;
    }
    __syncthreads();

    int srow = lane >> 2;
    int scol = (((lane & 3) ^ ((lane >> 3) & 3)) * 8);
    int slt = (lg ^ ((lr >> 1) & 3)) * 8;

    const unsigned short* gaA[2];
    const unsigned short* gaB[2];
    const unsigned short* gupE = gupT + (size_t)e * HDIM * F2;
#pragma unroll
    for (int i = 0; i < 2; ++i) {
        int arow = w * 32 + i * 16 + srow;
        int tk = rtok[arow];
        gaA[i] = (tk >= 0) ? (xb + (size_t)tk * HDIM + scol) : (zp + scol);
        int brow = n0 + w * 32 + i * 16 + srow;
        gaB[i] = gupE + (size_t)brow * HDIM + scol;
    }

    f32x4 acc[4][4];
#pragma unroll
    for (int m = 0; m < 4; ++m)
#pragma unroll
        for (int n = 0; n < 4; ++n) acc[m][n] = (f32x4){0.f, 0.f, 0.f, 0.f};

    KLOOP_PROLOGUE(32)
    KLOOP_BODY(HDIM / 32, 32)

    // epilogue: permuted B rows => acc[m][2q]=gate, acc[m][2q+1]=up of SAME feature, same lane
    unsigned short* actE = act + (size_t)e * CAP2 * NI;
    int fbase = nt * 64 + wc * 32;
#pragma unroll
    for (int q = 0; q < 2; ++q) {
        int f = fbase + q * 16 + lr;
        float bg = gub[e * F2 + 2 * f];
        float bu = gub[e * F2 + 2 * f + 1];
#pragma unroll
        for (int m = 0; m < 4; ++m) {
#pragma unroll
            for (int r = 0; r < 4; ++r) {
                float gate = acc[m][2 * q][r] + bg;
                float up   = acc[m][2 * q + 1][r] + bu;
                gate = fminf(gate, LIMIT);
                up   = fminf(fmaxf(up, -LIMIT), LIMIT);
                float glu = gate / (1.0f + __expf(-ALPHA * gate));
                float av  = (up + 1.0f) * glu;
                int row = row0 + wr * 64 + m * 16 + lg * 4 + r;
                actE[(size_t)row * NI + f] = f2bf(av);
            }
        }
    }
}

// ------- GEMM2 (tier A): act @ dwnT^T, *score, +bias -> compact bf16 y[base[e]+p][HDIM] -------
__global__ __launch_bounds__(256) void gemm2_y_kernel(
    const unsigned short* __restrict__ act, const unsigned short* __restrict__ dwnT,
    const float* __restrict__ dwb,
    const int* __restrict__ counts, const float* __restrict__ wgts,
    unsigned short* __restrict__ y)
{
    int b = blockIdx.x;
    int e = b & 15;
    int j = b >> 4;
    int nt = j & 7;
    int mt = j >> 3;
    int cnt = counts[e];
    int row0 = mt * 128;
    if (row0 >= cnt) return;
    int n0 = nt * 128;

    int base_e = 0;
#pragma unroll
    for (int q = 0; q < NE; ++q) base_e += (q < e) ? counts[q] : 0;

    __shared__ __align__(16) unsigned short As[3][128][32];
    __shared__ __align__(16) unsigned short Bs[3][128][32];
    __shared__ float rwgt[128];

    int tid = threadIdx.x;
    int lane = tid & 63;
    int w = tid >> 6;
    int wr = w >> 1, wc = w & 1;
    int lr = lane & 15, lg = lane >> 4;

    if (tid < 128) {
        int p = row0 + tid;
        rwgt[tid] = (p < cnt) ? wgts[e * CAP + p] : 0.0f;
    }
    __syncthreads();

    int srow = lane >> 2;
    int scol = (((lane & 3) ^ ((lane >> 3) & 3)) * 8);
    int slt = (lg ^ ((lr >> 1) & 3)) * 8;

    const unsigned short* gaA[2];
    const unsigned short* gaB[2];
    const unsigned short* actE = act + (size_t)e * CAP2 * NI;
    const unsigned short* dwnE = dwnT + (size_t)e * HDIM * NI;
#pragma unroll
    for (int i = 0; i < 2; ++i) {
        int arow = row0 + w * 32 + i * 16 + srow;
        gaA[i] = actE + (size_t)arow * NI + scol;
        int brow = n0 + w * 32 + i * 16 + srow;
        gaB[i] = dwnE + (size_t)brow * NI + scol;
    }

    f32x4 acc[4][4];
#pragma unroll
    for (int m = 0; m < 4; ++m)
#pragma unroll
        for (int n = 0; n < 4; ++n) acc[m][n] = (f32x4){0.f, 0.f, 0.f, 0.f};

    KLOOP_PROLOGUE(32)
    KLOOP_BODY(NI / 32, 32)

    unsigned short* yB = y + (size_t)(base_e + row0) * HDIM;
#pragma unroll
    for (int n = 0; n < 4; ++n) {
        int hc = n0 + wc * 64 + n * 16 + lr;
        float db = dwb[e * HDIM + hc];
#pragma unroll
        for (int m = 0; m < 4; ++m) {
#pragma unroll
            for (int r = 0; r < 4; ++r) {
                int rl = wr * 64 + m * 16 + lg * 4 + r;
                if (row0 + rl < cnt)
                    yB[(size_t)rl * HDIM + hc] = f2bf(rwgt[rl] * (acc[m][n][r] + db));
            }
        }
    }
}

// ------- out combine: out[t] = y[slot0] + y[slot1]; bf16 reads, coalesced, no atomics -------
__global__ __launch_bounds__(256) void out_combine_kernel(
    const unsigned short* __restrict__ y, const unsigned short* __restrict__ inv,
    const int* __restrict__ counts, float* __restrict__ out)
{
    __shared__ int sbase[NE];
    int tid = threadIdx.x;
    int t = blockIdx.x;
    if (tid == 0) {
        int s = 0;
#pragma unroll
        for (int e = 0; e < NE; ++e) { sbase[e] = s; s += counts[e]; }
    }
    __syncthreads();
    unsigned short v0 = inv[2 * t], v1 = inv[2 * t + 1];
    int s0 = sbase[v0 >> 11] + (v0 & 2047);
    int s1 = sbase[v1 >> 11] + (v1 & 2047);
    short4v a = *(const short4v*)(y + (size_t)s0 * HDIM + tid * 4);
    short4v c = *(const short4v*)(y + (size_t)s1 * HDIM + tid * 4);
    float4 o;
    o.x = bf2f((unsigned short)a[0]) + bf2f((unsigned short)c[0]);
    o.y = bf2f((unsigned short)a[1]) + bf2f((unsigned short)c[1]);
    o.z = bf2f((unsigned short)a[2]) + bf2f((unsigned short)c[2]);
    o.w = bf2f((unsigned short)a[3]) + bf2f((unsigned short)c[3]);
    *(float4*)(out + (size_t)t * HDIM + tid * 4) = o;
}

// ================= fallback path kernels (round-1 style, small ws) =================
__global__ __launch_bounds__(256) void router_kernel(
    const float* __restrict__ x, const float* __restrict__ rw,
    int* __restrict__ counts, int* __restrict__ toks, float* __restrict__ wgts)
{
    int gwave = (int)((blockIdx.x * 256 + threadIdx.x) >> 6);
    int lane = threadIdx.x & 63;
    if (gwave >= TOK) return;
    const float* xr = x + (size_t)gwave * HDIM;
    double acc[NE];
#pragma unroll
    for (int e = 0; e < NE; ++e) acc[e] = 0.0;
    for (int i = 0; i < HDIM / 64; ++i) {
        int h = i * 64 + lane;
        double xv = (double)xr[h];
        const float* r = rw + (size_t)h * NE;
#pragma unroll
        for (int e = 0; e < NE; ++e) acc[e] += xv * (double)r[e];
    }
#pragma unroll
    for (int e = 0; e < NE; ++e) {
        double v = acc[e];
#pragma unroll
        for (int off = 32; off > 0; off >>= 1) v += __shfl_xor(v, off);
        acc[e] = v;
    }
    if (lane == 0) {
        int i0 = 0; double v0 = acc[0];
#pragma unroll
        for (int e = 1; e < NE; ++e) if (acc[e] > v0) { v0 = acc[e]; i0 = e; }
        int i1 = -1; double v1 = -1e300;
#pragma unroll
        for (int e = 0; e < NE; ++e) if (e != i0 && acc[e] > v1) { v1 = acc[e]; i1 = e; }
        double e1 = exp(v1 - v0);
        float w0 = (float)(1.0 / (1.0 + e1));
        float w1 = (float)(e1 / (1.0 + e1));
        int p0 = atomicAdd(&counts[i0], 1);
        toks[i0 * CAP + p0] = gwave; wgts[i0 * CAP + p0] = w0;
        int p1 = atomicAdd(&counts[i1], 1);
        toks[i1 * CAP + p1] = gwave; wgts[i1 * CAP + p1] = w1;
    }
}

__global__ __launch_bounds__(256) void moe_kernel(
    const float* __restrict__ x,
    const float* __restrict__ gup, const float* __restrict__ gub,
    const float* __restrict__ dwn, const float* __restrict__ dwb,
    const int* __restrict__ counts, const int* __restrict__ toks,
    const float* __restrict__ wgts, float* __restrict__ out)
{
    int e = blockIdx.y;
    int cnt = counts[e];
    int row0 = blockIdx.x * 64;
    if (row0 >= cnt) return;

    __shared__ __align__(16) unsigned short sA[64][40];
    __shared__ __align__(16) unsigned short sB[64][40];
    __shared__ __align__(16) unsigned short sAct[64][520];
    __shared__ int   rtok[64];
    __shared__ float rwgt[64];

    int tid = threadIdx.x;
    if (tid < 64) {
        int idx = row0 + tid;
        bool v = idx < cnt;
        rtok[tid] = v ? toks[e * CAP + idx] : -1;
        rwgt[tid] = v ? wgts[e * CAP + idx] : 0.0f;
    }
    __syncthreads();

    int lane = tid & 63;
    int w = tid >> 6;
    int wr = w >> 1, wc = w & 1;
    int lr = lane & 15, lg = lane >> 4;
    int ar = tid >> 2, ac0 = (tid & 3) * 8;
    int bk = tid >> 3, bf0 = (tid & 7) * 8;
    const float* gupE = gup + (size_t)e * HDIM * F2;

    for (int nb = 0; nb < F2 / 64; ++nb) {
        f32x4 acc[2][2];
#pragma unroll
        for (int mi = 0; mi < 2; ++mi)
#pragma unroll
            for (int ni = 0; ni < 2; ++ni) acc[mi][ni] = (f32x4){0.f, 0.f, 0.f, 0.f};
        for (int kb = 0; kb < HDIM / 32; ++kb) {
            __syncthreads();
            {
                int tk = rtok[ar];
                short8 vv = {0,0,0,0,0,0,0,0};
                if (tk >= 0) {
                    const float* p = x + (size_t)tk * HDIM + kb * 32 + ac0;
                    float4 u0 = *(const float4*)(p); float4 u1 = *(const float4*)(p + 4);
                    vv[0]=(short)f2bf(u0.x); vv[1]=(short)f2bf(u0.y); vv[2]=(short)f2bf(u0.z); vv[3]=(short)f2bf(u0.w);
                    vv[4]=(short)f2bf(u1.x); vv[5]=(short)f2bf(u1.y); vv[6]=(short)f2bf(u1.z); vv[7]=(short)f2bf(u1.w);
                }
                *(short8*)&sA[ar][ac0] = vv;
            }
            {
                const float* p = gupE + (size_t)(kb * 32 + bk) * F2 + nb * 64 + bf0;
                float4 u0 = *(const float4*)(p); float4 u1 = *(const float4*)(p + 4);
                sB[bf0+0][bk]=f2bf(u0.x); sB[bf0+1][bk]=f2bf(u0.y); sB[bf0+2][bk]=f2bf(u0.z); sB[bf0+3][bk]=f2bf(u0.w);
                sB[bf0+4][bk]=f2bf(u1.x); sB[bf0+5][bk]=f2bf(u1.y); sB[bf0+6][bk]=f2bf(u1.z); sB[bf0+7][bk]=f2bf(u1.w);
            }
            __syncthreads();
            short8 a0 = *(const short8*)&sA[wr*32+lr][lg*8];
            short8 a1 = *(const short8*)&sA[wr*32+16+lr][lg*8];
            short8 b0 = *(const short8*)&sB[wc*32+lr][lg*8];
            short8 b1 = *(const short8*)&sB[wc*32+16+lr][lg*8];
            acc[0][0] = __builtin_amdgcn_mfma_f32_16x16x32_bf16(a0,b0,acc[0][0],0,0,0);
            acc[0][1] = __builtin_amdgcn_mfma_f32_16x16x32_bf16(a0,b1,acc[0][1],0,0,0);
            acc[1][0] = __builtin_amdgcn_mfma_f32_16x16x32_bf16(a1,b0,acc[1][0],0,0,0);
            acc[1][1] = __builtin_amdgcn_mfma_f32_16x16x32_bf16(a1,b1,acc[1][1],0,0,0);
        }
#pragma unroll
        for (int ni = 0; ni < 2; ++ni) {
            int fc = nb * 64 + wc * 32 + ni * 16 + lr;
            float bias = gub[e * F2 + fc];
#pragma unroll
            for (int mi = 0; mi < 2; ++mi)
#pragma unroll
                for (int r = 0; r < 4; ++r) {
                    float gu = acc[mi][ni][r] + bias;
                    float other = __shfl_xor(gu, 1);
                    float gate = (lr & 1) ? other : gu;
                    float up   = (lr & 1) ? gu : other;
                    gate = fminf(gate, LIMIT);
                    up = fminf(fmaxf(up, -LIMIT), LIMIT);
                    float glu = gate / (1.0f + __expf(-ALPHA * gate));
                    float av = (up + 1.0f) * glu;
                    if (!(lr & 1)) sAct[wr*32+mi*16+lg*4+r][fc >> 1] = f2bf(av);
                }
        }
    }
    __syncthreads();

    const float* dwnE = dwn + (size_t)e * NI * HDIM;
    int tks[2][4]; float wvs[2][4];
#pragma unroll
    for (int mi = 0; mi < 2; ++mi)
#pragma unroll
        for (int r = 0; r < 4; ++r) {
            int row = wr*32 + mi*16 + lg*4 + r;
            tks[mi][r] = rtok[row]; wvs[mi][r] = rwgt[row];
        }
    for (int nb = 0; nb < HDIM / 64; ++nb) {
        f32x4 acc[2][2];
#pragma unroll
        for (int mi = 0; mi < 2; ++mi)
#pragma unroll
            for (int ni = 0; ni < 2; ++ni) acc[mi][ni] = (f32x4){0.f,0.f,0.f,0.f};
        for (int kb = 0; kb < NI / 32; ++kb) {
            __syncthreads();
            {
                const float* p = dwnE + (size_t)(kb*32 + bk) * HDIM + nb*64 + bf0;
                float4 u0 = *(const float4*)(p); float4 u1 = *(const float4*)(p + 4);
                sB[bf0+0][bk]=f2bf(u0.x); sB[bf0+1][bk]=f2bf(u0.y); sB[bf0+2][bk]=f2bf(u0.z); sB[bf0+3][bk]=f2bf(u0.w);
                sB[bf0+4][bk]=f2bf(u1.x); sB[bf0+5][bk]=f2bf(u1.y); sB[bf0+6][bk]=f2bf(u1.z); sB[bf0+7][bk]=f2bf(u1.w);
            }
            __syncthreads();
            short8 a0 = *(const short8*)&sAct[wr*32+lr][kb*32+lg*8];
            short8 a1 = *(const short8*)&sAct[wr*32+16+lr][kb*32+lg*8];
            short8 b0 = *(const short8*)&sB[wc*32+lr][lg*8];
            short8 b1 = *(const short8*)&sB[wc*32+16+lr][lg*8];
            acc[0][0] = __builtin_amdgcn_mfma_f32_16x16x32_bf16(a0,b0,acc[0][0],0,0,0);
            acc[0][1] = __builtin_amdgcn_mfma_f32_16x16x32_bf16(a0,b1,acc[0][1],0,0,0);
            acc[1][0] = __builtin_amdgcn_mfma_f32_16x16x32_bf16(a1,b0,acc[1][0],0,0,0);
            acc[1][1] = __builtin_amdgcn_mfma_f32_16x16x32_bf16(a1,b1,acc[1][1],0,0,0);
        }
#pragma unroll
        for (int ni = 0; ni < 2; ++ni) {
            int hc = nb*64 + wc*32 + ni*16 + lr;
            float db = dwb[e * HDIM + hc];
#pragma unroll
            for (int mi = 0; mi < 2; ++mi)
#pragma unroll
                for (int r = 0; r < 4; ++r) {
                    int tk = tks[mi][r];
                    if (tk >= 0)
                        atomicAdd(out + (size_t)tk * HDIM + hc, wvs[mi][r] * (acc[mi][ni][r] + db));
                }
        }
    }
}

extern "C" void kernel_launch(void* const* d_in, const int* in_sizes, int n_in,
                              void* d_out, int out_size, void* d_ws, size_t ws_size,
                              hipStream_t stream) {
    const float* x   = (const float*)d_in[0];
    const float* rw  = (const float*)d_in[1];
    const float* gup = (const float*)d_in[2];
    const float* gub = (const float*)d_in[3];
    const float* dwn = (const float*)d_in[4];
    const float* dwb = (const float*)d_in[5];
    float* out = (float*)d_out;

    // ---- ws layout ----
    const size_t OFF_COUNTS = 0;                                   // 256 B
    const size_t OFF_ZP     = 256;                                 // 4 KB zero page
    const size_t OFF_INV    = 4352;                                // 32 KB
    const size_t OFF_TOKS   = OFF_INV  + (size_t)TOK * 2 * 2;
    const size_t OFF_WGTS   = OFF_TOKS + (size_t)NE * CAP * 4;
    const size_t OFF_DWNT   = OFF_WGTS + (size_t)NE * CAP * 4;
    const size_t OFF_ACT    = OFF_DWNT + (size_t)NE * NI * HDIM * 2;   // part (4MB) aliases here
    const size_t OFF_XBF    = OFF_ACT  + (size_t)NE * CAP2 * NI * 2;
    const size_t OFF_GUPT   = OFF_XBF  + (size_t)TOK * HDIM * 2;
    const size_t REQ_B      = OFF_GUPT + (size_t)NE * HDIM * F2 * 2;
    const size_t OFF_Y      = OFF_XBF;                             // aliases xbf+gupT (dead after gemm1)
    const size_t REQ_A      = OFF_Y + (size_t)2 * TOK * HDIM * 2;  // 32 MB compact bf16 y

    if (ws_size >= REQ_B) {
        int*            counts = (int*)((char*)d_ws + OFF_COUNTS);
        unsigned short* zp     = (unsigned short*)((char*)d_ws + OFF_ZP);
        unsigned short* inv    = (unsigned short*)((char*)d_ws + OFF_INV);
        int*            toks   = (int*)((char*)d_ws + OFF_TOKS);
        float*          wgts   = (float*)((char*)d_ws + OFF_WGTS);
        unsigned short* dwnT   = (unsigned short*)((char*)d_ws + OFF_DWNT);
        unsigned short* act    = (unsigned short*)((char*)d_ws + OFF_ACT);
        double*         part   = (double*)((char*)d_ws + OFF_ACT);
        unsigned short* xbf    = (unsigned short*)((char*)d_ws + OFF_XBF);
        unsigned short* gupT   = (unsigned short*)((char*)d_ws + OFF_GUPT);
        unsigned short* y      = (unsigned short*)((char*)d_ws + OFF_Y);

        hipMemsetAsync(d_ws, 0, 4352, stream);   // counts + zero page

        // fused prep: router partials (first, 512 blocks) + both weight transposes
        prep_kernel<<<512 + 1024 + 512, 256, 0, stream>>>(
            x, rw, gup, dwn, part, xbf, gupT, dwnT);

        router_combine_kernel<<<TOK / 256, 256, 0, stream>>>(part, counts, toks, wgts, inv);

        int g1 = (CAP2 / 128) * (F2 / 128) * NE;     // 2048
        gemm1_kernel<<<g1, 256, 0, stream>>>(xbf, gupT, gub, counts, toks, act, zp);
        int g2 = (CAP2 / 128) * (HDIM / 128) * NE;   // 2048

        if (ws_size >= REQ_A) {
            gemm2_y_kernel<<<g2, 256, 0, stream>>>(act, dwnT, dwb, counts, wgts, y);
            out_combine_kernel<<<TOK, 256, 0, stream>>>(y, inv, counts, out);
        } else {
            hipMemsetAsync(d_out, 0, (size_t)out_size * sizeof(float), stream);
            out_combine_kernel<<<TOK, 256, 0, stream>>>(y, inv, counts, out);
        }
    } else {
        // fallback: round-1 path (~1.1 MB of ws)
        int*   counts = (int*)d_ws;
        int*   toks   = (int*)((char*)d_ws + 64);
        float* wgts   = (float*)((char*)d_ws + 64 + (size_t)NE * CAP * sizeof(int));
        hipMemsetAsync(d_ws, 0, 64, stream);
        hipMemsetAsync(d_out, 0, (size_t)out_size * sizeof(float), stream);
        router_kernel<<<TOK / 4, 256, 0, stream>>>(x, rw, counts, toks, wgts);
        dim3 gm(TOK / 64, NE);
        moe_kernel<<<gm, 256, 0, stream>>>(x, gup, gub, dwn, dwb, counts, toks, wgts, out);
    }
}

// Round 12
// 156.765 us; speedup vs baseline: 1.1420x; 1.0198x over previous
//
#include <hip/hip_runtime.h>
#include <hip/hip_bf16.h>
#include <math.h>

#define TOK   8192
#define HDIM  1024
#define NE    16
#define NI    512
#define F2    1024
#define CAP   8192
#define CAP2  2048
#define ALPHA 1.702f
#define LIMIT 7.0f

typedef __attribute__((ext_vector_type(8))) short short8;
typedef __attribute__((ext_vector_type(4))) short short4v;
typedef __attribute__((ext_vector_type(4))) float f32x4;

static __device__ __forceinline__ unsigned short f2bf(float f) {
    unsigned int u = __float_as_uint(f);
    u += 0x7FFFu + ((u >> 16) & 1u);
    return (unsigned short)(u >> 16);
}
static __device__ __forceinline__ float bf2f(unsigned short u) {
    return __uint_as_float((unsigned int)u << 16);
}

#define GLD_LDS16(g, l) __builtin_amdgcn_global_load_lds(                     \
    (const __attribute__((address_space(1))) void*)(g),                       \
    (__attribute__((address_space(3))) void*)(l), 16, 0, 0)

// ================= fused prep: router partials FIRST, then weight transposes =================
// blocks [0,512):    router partial logits (4 waves/block) + x->bf16
// blocks [512,1536): gup [E][1024][1024] -> gupT [E][n(perm)][k] bf16   (64n x 256k tiles)
// blocks [1536,2048): dwn [E][512][1024] -> dwnT [E][n][k] bf16         (64n x 256k tiles)

// 64n x 256k transpose tile; XOR-swizzled LDS (16B blocks) -> staging writes 2-way max.
static __device__ __forceinline__ void do_transpose256(
    const float* __restrict__ in, unsigned short* __restrict__ out,
    int R, int C, int perm, int e, int bx, int by, char* smem, int tid)
{
    unsigned short (*t2)[264] = (unsigned short (*)[264])smem;   // [n][k], 33792 B
    const float* pin = in + (size_t)e * R * C;
    unsigned short* pout = out + (size_t)e * R * C;
    int c0 = bx * 64, r0 = by * 256;

    // read 256 k-rows x 64 n (row-pairs packed to dword LDS stores, swizzled cols)
#pragma unroll
    for (int j = 0; j < 8; ++j) {
        int idx = j * 256 + tid;               // 2048 = 128 r-pairs x 16 c4-groups
        int rp = idx >> 4, c4 = (idx & 15) * 4;
        int swz = ((c4 >> 2) & 7) << 3;        // rows c4..c4+3 share (row>>2)
        const float* p0 = pin + (size_t)(r0 + 2 * rp) * C + c0 + c4;
        float4 v0 = *(const float4*)(p0);
        float4 v1 = *(const float4*)(p0 + C);
        unsigned int u0 = (unsigned int)f2bf(v0.x) | ((unsigned int)f2bf(v1.x) << 16);
        unsigned int u1 = (unsigned int)f2bf(v0.y) | ((unsigned int)f2bf(v1.y) << 16);
        unsigned int u2 = (unsigned int)f2bf(v0.z) | ((unsigned int)f2bf(v1.z) << 16);
        unsigned int u3 = (unsigned int)f2bf(v0.w) | ((unsigned int)f2bf(v1.w) << 16);
        int kc = (2 * rp) ^ swz;
        *(unsigned int*)&t2[c4 + 0][kc] = u0;
        *(unsigned int*)&t2[c4 + 1][kc] = u1;
        *(unsigned int*)&t2[c4 + 2][kc] = u2;
        *(unsigned int*)&t2[c4 + 3][kc] = u3;
    }
    __syncthreads();

    // write 64 n-rows x 256 k: 32 lanes x short8 = 512B contiguous per row
#pragma unroll
    for (int j = 0; j < 8; ++j) {
        int idx = j * 256 + tid;               // 2048 = 64 n x 32 chunks
        int n = idx >> 5, k0 = (idx & 31) * 8;
        int rswz = ((n >> 2) & 7) << 3;
        short8 v = *(const short8*)&t2[n][k0 ^ rswz];
        int c = c0 + n;
        int orow;
        if (perm) {
            int tile = c >> 7, ct = c & 127;
            int fl = ct >> 1, h = ct & 1;
            orow = (tile << 7) | ((fl >> 4) << 5) | (h << 4) | (fl & 15);
        } else {
            orow = c;
        }
        *(short8*)(pout + (size_t)orow * R + r0 + k0) = v;
    }
}

__global__ __launch_bounds__(256) void prep_kernel(
    const float* __restrict__ x, const float* __restrict__ rw,
    const float* __restrict__ gup, const float* __restrict__ dwn,
    double* __restrict__ part, unsigned short* __restrict__ xbf,
    unsigned short* __restrict__ gupT, unsigned short* __restrict__ dwnT)
{
    __shared__ __align__(16) char smem[33792];
    int bid = blockIdx.x;
    int tid = threadIdx.x;

    if (bid >= 512) {
        if (bid < 1536) {
            int i = bid - 512;                 // gup: e(16) x ktile(4) x ntile(16)
            do_transpose256(gup, gupT, HDIM, F2, 1, i >> 6, i & 15, (i >> 4) & 3, smem, tid);
        } else {
            int i = bid - 1536;                // dwn: e(16) x ktile(2) x ntile(16)
            do_transpose256(dwn, dwnT, NI, HDIM, 0, i >> 5, i & 15, (i >> 4) & 1, smem, tid);
        }
        return;
    }

    // ---- router partials: 512 blocks x 4 waves; wave w handles (tile=bid, ksl=w) ----
    int idx = bid;
    int w = tid >> 6;
    int lane = tid & 63;
    int tt = lane & 15, eg = lane >> 4;
    int t0 = idx * 16;
    int hbase = w * 256;

    float* sx  = (float*)(smem + w * 8448);           // [16][68]
    float* srw = (float*)(smem + w * 8448 + 4352);    // [64][16]

    double acc[4] = {0.0, 0.0, 0.0, 0.0};

    for (int hc = 0; hc < 4; ++hc) {
        int h0 = hbase + hc * 64;
        __syncthreads();
#pragma unroll
        for (int j = 0; j < 4; ++j) {
            int fidx = j * 64 + lane;
            int t = fidx >> 4, c4 = (fidx & 15) * 4;
            float4 v = *(const float4*)(x + (size_t)(t0 + t) * HDIM + h0 + c4);
            *(float4*)&sx[t * 68 + c4] = v;
            short4v s;
            s[0] = (short)f2bf(v.x); s[1] = (short)f2bf(v.y);
            s[2] = (short)f2bf(v.z); s[3] = (short)f2bf(v.w);
            *(short4v*)(xbf + (size_t)(t0 + t) * HDIM + h0 + c4) = s;
        }
#pragma unroll
        for (int j = 0; j < 4; ++j) {
            int ridx = j * 64 + lane;
            int h = ridx >> 2, e4 = (ridx & 3) * 4;
            float4 v = *(const float4*)(rw + (size_t)(h0 + h) * NE + e4);
            *(float4*)&srw[h * 16 + e4] = v;
        }
        __syncthreads();
#pragma unroll 8
        for (int j = 0; j < 64; ++j) {
            float xv = sx[tt * 68 + j];
            float4 wv = *(const float4*)&srw[j * 16 + eg * 4];
            double xd = (double)xv;
            acc[0] += xd * (double)wv.x;
            acc[1] += xd * (double)wv.y;
            acc[2] += xd * (double)wv.z;
            acc[3] += xd * (double)wv.w;
        }
    }
#pragma unroll
    for (int q = 0; q < 4; ++q)
        part[(size_t)(w * NE + eg * 4 + q) * TOK + t0 + tt] = acc[q];
}

// ===== router phase B: combine, top-2, softmax, aggregated scatter + inverse map =====
__global__ __launch_bounds__(256) void router_combine_kernel(
    const double* __restrict__ part,
    int* __restrict__ counts, int* __restrict__ toks, float* __restrict__ wgts,
    unsigned short* __restrict__ inv)
{
    __shared__ int lhist[NE];
    __shared__ int lbase[NE];
    int tid = threadIdx.x;
    int t = blockIdx.x * 256 + tid;
    if (tid < NE) lhist[tid] = 0;
    __syncthreads();

    double acc[NE];
#pragma unroll
    for (int e = 0; e < NE; ++e)
        acc[e] = part[(size_t)(0 * NE + e) * TOK + t]
               + part[(size_t)(1 * NE + e) * TOK + t]
               + part[(size_t)(2 * NE + e) * TOK + t]
               + part[(size_t)(3 * NE + e) * TOK + t];

    int i0 = 0; double v0 = acc[0];
#pragma unroll
    for (int e = 1; e < NE; ++e) if (acc[e] > v0) { v0 = acc[e]; i0 = e; }
    int i1 = -1; double v1 = -1e300;
#pragma unroll
    for (int e = 0; e < NE; ++e) if (e != i0 && acc[e] > v1) { v1 = acc[e]; i1 = e; }
    double e1 = exp(v1 - v0);
    float w0 = (float)(1.0 / (1.0 + e1));
    float w1 = (float)(e1 / (1.0 + e1));

    int r0 = atomicAdd(&lhist[i0], 1);
    int r1 = atomicAdd(&lhist[i1], 1);
    __syncthreads();
    if (tid < NE) lbase[tid] = atomicAdd(&counts[tid], lhist[tid]);
    __syncthreads();
    int p0 = lbase[i0] + r0; if (p0 > 2047) p0 = 2047;
    int p1 = lbase[i1] + r1; if (p1 > 2047) p1 = 2047;
    toks[i0 * CAP + p0] = t; wgts[i0 * CAP + p0] = w0;
    toks[i1 * CAP + p1] = t; wgts[i1 * CAP + p1] = w1;
    inv[2 * t]     = (unsigned short)((i0 << 11) | p0);
    inv[2 * t + 1] = (unsigned short)((i1 << 11) | p1);
}

// ===== 3-buffer counted-vmcnt K-loop (T3/T4, prefetch depth 2) — R8-verified =====
#define KLOOP_BODY(NT, KOFF)                                                          \
    int c0 = 0;                                                                       \
    for (int kb = 0; kb < (NT); ++kb) {                                               \
        if (kb + 2 < (NT)) {                                                          \
            int cpre = c0 + 2; if (cpre >= 3) cpre -= 3;                              \
            _Pragma("unroll")                                                         \
            for (int i = 0; i < 2; ++i) {                                             \
                GLD_LDS16(gaA[i] + (kb + 2) * (KOFF), &As[cpre][w * 32 + i * 16][0]); \
                GLD_LDS16(gaB[i] + (kb + 2) * (KOFF), &Bs[cpre][w * 32 + i * 16][0]); \
            }                                                                         \
            asm volatile("s_waitcnt vmcnt(8)" ::: "memory");                          \
        } else if (kb + 1 < (NT)) {                                                   \
            asm volatile("s_waitcnt vmcnt(4)" ::: "memory");                          \
        } else {                                                                      \
            asm volatile("s_waitcnt vmcnt(0)" ::: "memory");                          \
        }                                                                             \
        __builtin_amdgcn_sched_barrier(0);                                            \
        __builtin_amdgcn_s_barrier();                                                 \
        __builtin_amdgcn_sched_barrier(0);                                            \
        short8 af[4], bfr[4];                                                         \
        _Pragma("unroll")                                                             \
        for (int m = 0; m < 4; ++m) af[m] = *(const short8*)&As[c0][wr * 64 + m * 16 + lr][slt]; \
        _Pragma("unroll")                                                             \
        for (int n = 0; n < 4; ++n) bfr[n] = *(const short8*)&Bs[c0][wc * 64 + n * 16 + lr][slt]; \
        _Pragma("unroll")                                                             \
        for (int m = 0; m < 4; ++m)                                                   \
            _Pragma("unroll")                                                         \
            for (int n = 0; n < 4; ++n)                                               \
                acc[m][n] = __builtin_amdgcn_mfma_f32_16x16x32_bf16(af[m], bfr[n], acc[m][n], 0, 0, 0); \
        asm volatile("s_waitcnt lgkmcnt(0)" ::: "memory");                            \
        __builtin_amdgcn_sched_barrier(0);                                            \
        __builtin_amdgcn_s_barrier();                                                 \
        __builtin_amdgcn_sched_barrier(0);                                            \
        c0 = (c0 + 1 == 3) ? 0 : c0 + 1;                                              \
    }

#define KLOOP_PROLOGUE(KOFF)                                                          \
    _Pragma("unroll")                                                                 \
    for (int i = 0; i < 2; ++i) {                                                     \
        GLD_LDS16(gaA[i], &As[0][w * 32 + i * 16][0]);                                \
        GLD_LDS16(gaB[i], &Bs[0][w * 32 + i * 16][0]);                                \
    }                                                                                 \
    _Pragma("unroll")                                                                 \
    for (int i = 0; i < 2; ++i) {                                                     \
        GLD_LDS16(gaA[i] + (KOFF), &As[1][w * 32 + i * 16][0]);                       \
        GLD_LDS16(gaB[i] + (KOFF), &Bs[1][w * 32 + i * 16][0]);                       \
    }

// ---------------- GEMM1: x_bf (gathered) @ gupT^T + bias -> act (bf16) ----------------
__global__ __launch_bounds__(256) void gemm1_kernel(
    const unsigned short* __restrict__ xb, const unsigned short* __restrict__ gupT,
    const float* __restrict__ gub,
    const int* __restrict__ counts, const int* __restrict__ toks,
    unsigned short* __restrict__ act, const unsigned short* __restrict__ zp)
{
    int b = blockIdx.x;
    int e = b & 15;
    int j = b >> 4;
    int nt = j & 7;
    int mt = j >> 3;
    int cnt = counts[e];
    int row0 = mt * 128;
    if (row0 >= cnt) return;
    int n0 = nt * 128;

    __shared__ __align__(16) unsigned short As[3][128][32];
    __shared__ __align__(16) unsigned short Bs[3][128][32];
    __shared__ int rtok[128];

    int tid = threadIdx.x;
    int lane = tid & 63;
    int w = tid >> 6;
    int wr = w >> 1, wc = w & 1;
    int lr = lane & 15, lg = lane >> 4;

    if (tid < 128) {
        int p = row0 + tid;
        rtok[tid] = (p < cnt) ? toks[e * CAP + p] : -1;
    }
    __syncthreads();

    int srow = lane >> 2;
    int scol = (((lane & 3) ^ ((lane >> 3) & 3)) * 8);
    int slt = (lg ^ ((lr >> 1) & 3)) * 8;

    const unsigned short* gaA[2];
    const unsigned short* gaB[2];
    const unsigned short* gupE = gupT + (size_t)e * HDIM * F2;
#pragma unroll
    for (int i = 0; i < 2; ++i) {
        int arow = w * 32 + i * 16 + srow;
        int tk = rtok[arow];
        gaA[i] = (tk >= 0) ? (xb + (size_t)tk * HDIM + scol) : (zp + scol);
        int brow = n0 + w * 32 + i * 16 + srow;
        gaB[i] = gupE + (size_t)brow * HDIM + scol;
    }

    f32x4 acc[4][4];
#pragma unroll
    for (int m = 0; m < 4; ++m)
#pragma unroll
        for (int n = 0; n < 4; ++n) acc[m][n] = (f32x4){0.f, 0.f, 0.f, 0.f};

    KLOOP_PROLOGUE(32)
    KLOOP_BODY(HDIM / 32, 32)

    // epilogue: permuted B rows => acc[m][2q]=gate, acc[m][2q+1]=up of SAME feature, same lane
    unsigned short* actE = act + (size_t)e * CAP2 * NI;
    int fbase = nt * 64 + wc * 32;
#pragma unroll
    for (int q = 0; q < 2; ++q) {
        int f = fbase + q * 16 + lr;
        float bg = gub[e * F2 + 2 * f];
        float bu = gub[e * F2 + 2 * f + 1];
#pragma unroll
        for (int m = 0; m < 4; ++m) {
#pragma unroll
            for (int r = 0; r < 4; ++r) {
                float gate = acc[m][2 * q][r] + bg;
                float up   = acc[m][2 * q + 1][r] + bu;
                gate = fminf(gate, LIMIT);
                up   = fminf(fmaxf(up, -LIMIT), LIMIT);
                float glu = gate / (1.0f + __expf(-ALPHA * gate));
                float av  = (up + 1.0f) * glu;
                int row = row0 + wr * 64 + m * 16 + lg * 4 + r;
                actE[(size_t)row * NI + f] = f2bf(av);
            }
        }
    }
}

// ------- GEMM2 (tier A): act @ dwnT^T, *score, +bias -> compact bf16 y[base[e]+p][HDIM] -------
__global__ __launch_bounds__(256) void gemm2_y_kernel(
    const unsigned short* __restrict__ act, const unsigned short* __restrict__ dwnT,
    const float* __restrict__ dwb,
    const int* __restrict__ counts, const float* __restrict__ wgts,
    unsigned short* __restrict__ y)
{
    int b = blockIdx.x;
    int e = b & 15;
    int j = b >> 4;
    int nt = j & 7;
    int mt = j >> 3;
    int cnt = counts[e];
    int row0 = mt * 128;
    if (row0 >= cnt) return;
    int n0 = nt * 128;

    int base_e = 0;
#pragma unroll
    for (int q = 0; q < NE; ++q) base_e += (q < e) ? counts[q] : 0;

    __shared__ __align__(16) unsigned short As[3][128][32];
    __shared__ __align__(16) unsigned short Bs[3][128][32];
    __shared__ float rwgt[128];

    int tid = threadIdx.x;
    int lane = tid & 63;
    int w = tid >> 6;
    int wr = w >> 1, wc = w & 1;
    int lr = lane & 15, lg = lane >> 4;

    if (tid < 128) {
        int p = row0 + tid;
        rwgt[tid] = (p < cnt) ? wgts[e * CAP + p] : 0.0f;
    }
    __syncthreads();

    int srow = lane >> 2;
    int scol = (((lane & 3) ^ ((lane >> 3) & 3)) * 8);
    int slt = (lg ^ ((lr >> 1) & 3)) * 8;

    const unsigned short* gaA[2];
    const unsigned short* gaB[2];
    const unsigned short* actE = act + (size_t)e * CAP2 * NI;
    const unsigned short* dwnE = dwnT + (size_t)e * HDIM * NI;
#pragma unroll
    for (int i = 0; i < 2; ++i) {
        int arow = row0 + w * 32 + i * 16 + srow;
        gaA[i] = actE + (size_t)arow * NI + scol;
        int brow = n0 + w * 32 + i * 16 + srow;
        gaB[i] = dwnE + (size_t)brow * NI + scol;
    }

    f32x4 acc[4][4];
#pragma unroll
    for (int m = 0; m < 4; ++m)
#pragma unroll
        for (int n = 0; n < 4; ++n) acc[m][n] = (f32x4){0.f, 0.f, 0.f, 0.f};

    KLOOP_PROLOGUE(32)
    KLOOP_BODY(NI / 32, 32)

    unsigned short* yB = y + (size_t)(base_e + row0) * HDIM;
#pragma unroll
    for (int n = 0; n < 4; ++n) {
        int hc = n0 + wc * 64 + n * 16 + lr;
        float db = dwb[e * HDIM + hc];
#pragma unroll
        for (int m = 0; m < 4; ++m) {
#pragma unroll
            for (int r = 0; r < 4; ++r) {
                int rl = wr * 64 + m * 16 + lg * 4 + r;
                if (row0 + rl < cnt)
                    yB[(size_t)rl * HDIM + hc] = f2bf(rwgt[rl] * (acc[m][n][r] + db));
            }
        }
    }
}

// ------- out combine: out[t] = y[slot0] + y[slot1]; bf16 reads, coalesced, no atomics -------
__global__ __launch_bounds__(256) void out_combine_kernel(
    const unsigned short* __restrict__ y, const unsigned short* __restrict__ inv,
    const int* __restrict__ counts, float* __restrict__ out)
{
    __shared__ int sbase[NE];
    int tid = threadIdx.x;
    int t = blockIdx.x;
    if (tid == 0) {
        int s = 0;
#pragma unroll
        for (int e = 0; e < NE; ++e) { sbase[e] = s; s += counts[e]; }
    }
    __syncthreads();
    unsigned short v0 = inv[2 * t], v1 = inv[2 * t + 1];
    int s0 = sbase[v0 >> 11] + (v0 & 2047);
    int s1 = sbase[v1 >> 11] + (v1 & 2047);
    short4v a = *(const short4v*)(y + (size_t)s0 * HDIM + tid * 4);
    short4v c = *(const short4v*)(y + (size_t)s1 * HDIM + tid * 4);
    float4 o;
    o.x = bf2f((unsigned short)a[0]) + bf2f((unsigned short)c[0]);
    o.y = bf2f((unsigned short)a[1]) + bf2f((unsigned short)c[1]);
    o.z = bf2f((unsigned short)a[2]) + bf2f((unsigned short)c[2]);
    o.w = bf2f((unsigned short)a[3]) + bf2f((unsigned short)c[3]);
    *(float4*)(out + (size_t)t * HDIM + tid * 4) = o;
}

// ================= fallback path kernels (round-1 style, small ws) =================
__global__ __launch_bounds__(256) void router_kernel(
    const float* __restrict__ x, const float* __restrict__ rw,
    int* __restrict__ counts, int* __restrict__ toks, float* __restrict__ wgts)
{
    int gwave = (int)((blockIdx.x * 256 + threadIdx.x) >> 6);
    int lane = threadIdx.x & 63;
    if (gwave >= TOK) return;
    const float* xr = x + (size_t)gwave * HDIM;
    double acc[NE];
#pragma unroll
    for (int e = 0; e < NE; ++e) acc[e] = 0.0;
    for (int i = 0; i < HDIM / 64; ++i) {
        int h = i * 64 + lane;
        double xv = (double)xr[h];
        const float* r = rw + (size_t)h * NE;
#pragma unroll
        for (int e = 0; e < NE; ++e) acc[e] += xv * (double)r[e];
    }
#pragma unroll
    for (int e = 0; e < NE; ++e) {
        double v = acc[e];
#pragma unroll
        for (int off = 32; off > 0; off >>= 1) v += __shfl_xor(v, off);
        acc[e] = v;
    }
    if (lane == 0) {
        int i0 = 0; double v0 = acc[0];
#pragma unroll
        for (int e = 1; e < NE; ++e) if (acc[e] > v0) { v0 = acc[e]; i0 = e; }
        int i1 = -1; double v1 = -1e300;
#pragma unroll
        for (int e = 0; e < NE; ++e) if (e != i0 && acc[e] > v1) { v1 = acc[e]; i1 = e; }
        double e1 = exp(v1 - v0);
        float w0 = (float)(1.0 / (1.0 + e1));
        float w1 = (float)(e1 / (1.0 + e1));
        int p0 = atomicAdd(&counts[i0], 1);
        toks[i0 * CAP + p0] = gwave; wgts[i0 * CAP + p0] = w0;
        int p1 = atomicAdd(&counts[i1], 1);
        toks[i1 * CAP + p1] = gwave; wgts[i1 * CAP + p1] = w1;
    }
}

__global__ __launch_bounds__(256) void moe_kernel(
    const float* __restrict__ x,
    const float* __restrict__ gup, const float* __restrict__ gub,
    const float* __restrict__ dwn, const float* __restrict__ dwb,
    const int* __restrict__ counts, const int* __restrict__ toks,
    const float* __restrict__ wgts, float* __restrict__ out)
{
    int e = blockIdx.y;
    int cnt = counts[e];
    int row0 = blockIdx.x * 64;
    if (row0 >= cnt) return;

    __shared__ __align__(16) unsigned short sA[64][40];
    __shared__ __align__(16) unsigned short sB[64][40];
    __shared__ __align__(16) unsigned short sAct[64][520];
    __shared__ int   rtok[64];
    __shared__ float rwgt[64];

    int tid = threadIdx.x;
    if (tid < 64) {
        int idx = row0 + tid;
        bool v = idx < cnt;
        rtok[tid] = v ? toks[e * CAP + idx] : -1;
        rwgt[tid] = v ? wgts[e * CAP + idx] : 0.0f;
    }
    __syncthreads();

    int lane = tid & 63;
    int w = tid >> 6;
    int wr = w >> 1, wc = w & 1;
    int lr = lane & 15, lg = lane >> 4;
    int ar = tid >> 2, ac0 = (tid & 3) * 8;
    int bk = tid >> 3, bf0 = (tid & 7) * 8;
    const float* gupE = gup + (size_t)e * HDIM * F2;

    for (int nb = 0; nb < F2 / 64; ++nb) {
        f32x4 acc[2][2];
#pragma unroll
        for (int mi = 0; mi < 2; ++mi)
#pragma unroll
            for (int ni = 0; ni < 2; ++ni) acc[mi][ni] = (f32x4){0.f, 0.f, 0.f, 0.f};
        for (int kb = 0; kb < HDIM / 32; ++kb) {
            __syncthreads();
            {
                int tk = rtok[ar];
                short8 vv = {0,0,0,0,0,0,0,0};
                if (tk >= 0) {
                    const float* p = x + (size_t)tk * HDIM + kb * 32 + ac0;
                    float4 u0 = *(const float4*)(p); float4 u1 = *(const float4*)(p + 4);
                    vv[0]=(short)f2bf(u0.x); vv[1]=(short)f2bf(u0.y); vv[2]=(short)f2bf(u0.z); vv[3]=(short)f2bf(u0.w);
                    vv[4]=(short)f2bf(u1.x); vv[5]=(short)f2bf(u1.y); vv[6]=(short)f2bf(u1.z); vv[7]=(short)f2bf(u1.w);
                }
                *(short8*)&sA[ar][ac0] = vv;
            }
            {
                const float* p = gupE + (size_t)(kb * 32 + bk) * F2 + nb * 64 + bf0;
                float4 u0 = *(const float4*)(p); float4 u1 = *(const float4*)(p + 4);
                sB[bf0+0][bk]=f2bf(u0.x); sB[bf0+1][bk]=f2bf(u0.y); sB[bf0+2][bk]=f2bf(u0.z); sB[bf0+3][bk]=f2bf(u0.w);
                sB[bf0+4][bk]=f2bf(u1.x); sB[bf0+5][bk]=f2bf(u1.y); sB[bf0+6][bk]=f2bf(u1.z); sB[bf0+7][bk]=f2bf(u1.w);
            }
            __syncthreads();
            short8 a0 = *(const short8*)&sA[wr*32+lr][lg*8];
            short8 a1 = *(const short8*)&sA[wr*32+16+lr][lg*8];
            short8 b0 = *(const short8*)&sB[wc*32+lr][lg*8];
            short8 b1 = *(const short8*)&sB[wc*32+16+lr][lg*8];
            acc[0][0] = __builtin_amdgcn_mfma_f32_16x16x32_bf16(a0,b0,acc[0][0],0,0,0);
            acc[0][1] = __builtin_amdgcn_mfma_f32_16x16x32_bf16(a0,b1,acc[0][1],0,0,0);
            acc[1][0] = __builtin_amdgcn_mfma_f32_16x16x32_bf16(a1,b0,acc[1][0],0,0,0);
            acc[1][1] = __builtin_amdgcn_mfma_f32_16x16x32_bf16(a1,b1,acc[1][1],0,0,0);
        }
#pragma unroll
        for (int ni = 0; ni < 2; ++ni) {
            int fc = nb * 64 + wc * 32 + ni * 16 + lr;
            float bias = gub[e * F2 + fc];
#pragma unroll
            for (int mi = 0; mi < 2; ++mi)
#pragma unroll
                for (int r = 0; r < 4; ++r) {
                    float gu = acc[mi][ni][r] + bias;
                    float other = __shfl_xor(gu, 1);
                    float gate = (lr & 1) ? other : gu;
                    float up   = (lr & 1) ? gu : other;
                    gate = fminf(gate, LIMIT);
                    up = fminf(fmaxf(up, -LIMIT), LIMIT);
                    float glu = gate / (1.0f + __expf(-ALPHA * gate));
                    float av = (up + 1.0f) * glu;
                    if (!(lr & 1)) sAct[wr*32+mi*16+lg*4+r][fc >> 1] = f2bf(av);
                }
        }
    }
    __syncthreads();

    const float* dwnE = dwn + (size_t)e * NI * HDIM;
    int tks[2][4]; float wvs[2][4];
#pragma unroll
    for (int mi = 0; mi < 2; ++mi)
#pragma unroll
        for (int r = 0; r < 4; ++r) {
            int row = wr*32 + mi*16 + lg*4 + r;
            tks[mi][r] = rtok[row]; wvs[mi][r] = rwgt[row];
        }
    for (int nb = 0; nb < HDIM / 64; ++nb) {
        f32x4 acc[2][2];
#pragma unroll
        for (int mi = 0; mi < 2; ++mi)
#pragma unroll
            for (int ni = 0; ni < 2; ++ni) acc[mi][ni] = (f32x4){0.f,0.f,0.f,0.f};
        for (int kb = 0; kb < NI / 32; ++kb) {
            __syncthreads();
            {
                const float* p = dwnE + (size_t)(kb*32 + bk) * HDIM + nb*64 + bf0;
                float4 u0 = *(const float4*)(p); float4 u1 = *(const float4*)(p + 4);
                sB[bf0+0][bk]=f2bf(u0.x); sB[bf0+1][bk]=f2bf(u0.y); sB[bf0+2][bk]=f2bf(u0.z); sB[bf0+3][bk]=f2bf(u0.w);
                sB[bf0+4][bk]=f2bf(u1.x); sB[bf0+5][bk]=f2bf(u1.y); sB[bf0+6][bk]=f2bf(u1.z); sB[bf0+7][bk]=f2bf(u1.w);
            }
            __syncthreads();
            short8 a0 = *(const short8*)&sAct[wr*32+lr][kb*32+lg*8];
            short8 a1 = *(const short8*)&sAct[wr*32+16+lr][kb*32+lg*8];
            short8 b0 = *(const short8*)&sB[wc*32+lr][lg*8];
            short8 b1 = *(const short8*)&sB[wc*32+16+lr][lg*8];
            acc[0][0] = __builtin_amdgcn_mfma_f32_16x16x32_bf16(a0,b0,acc[0][0],0,0,0);
            acc[0][1] = __builtin_amdgcn_mfma_f32_16x16x32_bf16(a0,b1,acc[0][1],0,0,0);
            acc[1][0] = __builtin_amdgcn_mfma_f32_16x16x32_bf16(a1,b0,acc[1][0],0,0,0);
            acc[1][1] = __builtin_amdgcn_mfma_f32_16x16x32_bf16(a1,b1,acc[1][1],0,0,0);
        }
#pragma unroll
        for (int ni = 0; ni < 2; ++ni) {
            int hc = nb*64 + wc*32 + ni*16 + lr;
            float db = dwb[e * HDIM + hc];
#pragma unroll
            for (int mi = 0; mi < 2; ++mi)
#pragma unroll
                for (int r = 0; r < 4; ++r) {
                    int tk = tks[mi][r];
                    if (tk >= 0)
                        atomicAdd(out + (size_t)tk * HDIM + hc, wvs[mi][r] * (acc[mi][ni][r] + db));
                }
        }
    }
}

extern "C" void kernel_launch(void* const* d_in, const int* in_sizes, int n_in,
                              void* d_out, int out_size, void* d_ws, size_t ws_size,
                              hipStream_t stream) {
    const float* x   = (const float*)d_in[0];
    const float* rw  = (const float*)d_in[1];
    const float* gup = (const float*)d_in[2];
    const float* gub = (const float*)d_in[3];
    const float* dwn = (const float*)d_in[4];
    const float* dwb = (const float*)d_in[5];
    float* out = (float*)d_out;

    // ---- ws layout ----
    const size_t OFF_COUNTS = 0;                                   // 256 B
    const size_t OFF_ZP     = 256;                                 // 4 KB zero page
    const size_t OFF_INV    = 4352;                                // 32 KB
    const size_t OFF_TOKS   = OFF_INV  + (size_t)TOK * 2 * 2;
    const size_t OFF_WGTS   = OFF_TOKS + (size_t)NE * CAP * 4;
    const size_t OFF_DWNT   = OFF_WGTS + (size_t)NE * CAP * 4;
    const size_t OFF_ACT    = OFF_DWNT + (size_t)NE * NI * HDIM * 2;   // part (4MB) aliases here
    const size_t OFF_XBF    = OFF_ACT  + (size_t)NE * CAP2 * NI * 2;
    const size_t OFF_GUPT   = OFF_XBF  + (size_t)TOK * HDIM * 2;
    const size_t REQ_B      = OFF_GUPT + (size_t)NE * HDIM * F2 * 2;
    const size_t OFF_Y      = OFF_XBF;                             // aliases xbf+gupT (dead after gemm1)
    const size_t REQ_A      = OFF_Y + (size_t)2 * TOK * HDIM * 2;  // 32 MB compact bf16 y

    if (ws_size >= REQ_B) {
        int*            counts = (int*)((char*)d_ws + OFF_COUNTS);
        unsigned short* zp     = (unsigned short*)((char*)d_ws + OFF_ZP);
        unsigned short* inv    = (unsigned short*)((char*)d_ws + OFF_INV);
        int*            toks   = (int*)((char*)d_ws + OFF_TOKS);
        float*          wgts   = (float*)((char*)d_ws + OFF_WGTS);
        unsigned short* dwnT   = (unsigned short*)((char*)d_ws + OFF_DWNT);
        unsigned short* act    = (unsigned short*)((char*)d_ws + OFF_ACT);
        double*         part   = (double*)((char*)d_ws + OFF_ACT);
        unsigned short* xbf    = (unsigned short*)((char*)d_ws + OFF_XBF);
        unsigned short* gupT   = (unsigned short*)((char*)d_ws + OFF_GUPT);
        unsigned short* y      = (unsigned short*)((char*)d_ws + OFF_Y);

        hipMemsetAsync(d_ws, 0, 4352, stream);   // counts + zero page

        // fused prep: router partials (first, 512 blocks) + both weight transposes
        prep_kernel<<<512 + 1024 + 512, 256, 0, stream>>>(
            x, rw, gup, dwn, part, xbf, gupT, dwnT);

        router_combine_kernel<<<TOK / 256, 256, 0, stream>>>(part, counts, toks, wgts, inv);

        int g1 = (CAP2 / 128) * (F2 / 128) * NE;     // 2048
        gemm1_kernel<<<g1, 256, 0, stream>>>(xbf, gupT, gub, counts, toks, act, zp);
        int g2 = (CAP2 / 128) * (HDIM / 128) * NE;   // 2048

        if (ws_size >= REQ_A) {
            gemm2_y_kernel<<<g2, 256, 0, stream>>>(act, dwnT, dwb, counts, wgts, y);
            out_combine_kernel<<<TOK, 256, 0, stream>>>(y, inv, counts, out);
        } else {
            hipMemsetAsync(d_out, 0, (size_t)out_size * sizeof(float), stream);
            out_combine_kernel<<<TOK, 256, 0, stream>>>(y, inv, counts, out);
        }
    } else {
        // fallback: round-1 path (~1.1 MB of ws)
        int*   counts = (int*)d_ws;
        int*   toks   = (int*)((char*)d_ws + 64);
        float* wgts   = (float*)((char*)d_ws + 64 + (size_t)NE * CAP * sizeof(int));
        hipMemsetAsync(d_ws, 0, 64, stream);
        hipMemsetAsync(d_out, 0, (size_t)out_size * sizeof(float), stream);
        router_kernel<<<TOK / 4, 256, 0, stream>>>(x, rw, counts, toks, wgts);
        dim3 gm(TOK / 64, NE);
        moe_kernel<<<gm, 256, 0, stream>>>(x, gup, gub, dwn, dwb, counts, toks, wgts, out);
    }
}

// Round 13
// 149.391 us; speedup vs baseline: 1.1983x; 1.0494x over previous
//
#include <hip/hip_runtime.h>
#include <hip/hip_bf16.h>
#include <math.h>

#define TOK   8192
#define HDIM  1024
#define NE    16
#define NI    512
#define F2    1024
#define CAP   8192
#define CAP2  2048
#define ALPHA 1.702f
#define LIMIT 7.0f

typedef __attribute__((ext_vector_type(8))) short short8;
typedef __attribute__((ext_vector_type(4))) short short4v;
typedef __attribute__((ext_vector_type(4))) float f32x4;

static __device__ __forceinline__ unsigned short f2bf(float f) {
    unsigned int u = __float_as_uint(f);
    u += 0x7FFFu + ((u >> 16) & 1u);
    return (unsigned short)(u >> 16);
}
static __device__ __forceinline__ float bf2f(unsigned short u) {
    return __uint_as_float((unsigned int)u << 16);
}

#define GLD_LDS16(g, l) __builtin_amdgcn_global_load_lds(                     \
    (const __attribute__((address_space(1))) void*)(g),                       \
    (__attribute__((address_space(3))) void*)(l), 16, 0, 0)

// ===== 64n x 256k transpose tile; XOR-swizzled LDS; 512B-contiguous output runs =====
static __device__ __forceinline__ void do_transpose256(
    const float* __restrict__ in, unsigned short* __restrict__ out,
    int R, int C, int perm, int e, int bx, int by, char* smem, int tid)
{
    unsigned short (*t2)[264] = (unsigned short (*)[264])smem;   // [n][k], 33792 B
    const float* pin = in + (size_t)e * R * C;
    unsigned short* pout = out + (size_t)e * R * C;
    int c0 = bx * 64, r0 = by * 256;

#pragma unroll
    for (int j = 0; j < 8; ++j) {
        int idx = j * 256 + tid;               // 2048 = 128 r-pairs x 16 c4-groups
        int rp = idx >> 4, c4 = (idx & 15) * 4;
        int swz = ((c4 >> 2) & 7) << 3;
        const float* p0 = pin + (size_t)(r0 + 2 * rp) * C + c0 + c4;
        float4 v0 = *(const float4*)(p0);
        float4 v1 = *(const float4*)(p0 + C);
        unsigned int u0 = (unsigned int)f2bf(v0.x) | ((unsigned int)f2bf(v1.x) << 16);
        unsigned int u1 = (unsigned int)f2bf(v0.y) | ((unsigned int)f2bf(v1.y) << 16);
        unsigned int u2 = (unsigned int)f2bf(v0.z) | ((unsigned int)f2bf(v1.z) << 16);
        unsigned int u3 = (unsigned int)f2bf(v0.w) | ((unsigned int)f2bf(v1.w) << 16);
        int kc = (2 * rp) ^ swz;
        *(unsigned int*)&t2[c4 + 0][kc] = u0;
        *(unsigned int*)&t2[c4 + 1][kc] = u1;
        *(unsigned int*)&t2[c4 + 2][kc] = u2;
        *(unsigned int*)&t2[c4 + 3][kc] = u3;
    }
    __syncthreads();

#pragma unroll
    for (int j = 0; j < 8; ++j) {
        int idx = j * 256 + tid;               // 2048 = 64 n x 32 chunks
        int n = idx >> 5, k0 = (idx & 31) * 8;
        int rswz = ((n >> 2) & 7) << 3;
        short8 v = *(const short8*)&t2[n][k0 ^ rswz];
        int c = c0 + n;
        int orow;
        if (perm) {
            int tile = c >> 7, ct = c & 127;
            int fl = ct >> 1, h = ct & 1;
            orow = (tile << 7) | ((fl >> 4) << 5) | (h << 4) | (fl & 15);
        } else {
            orow = c;
        }
        *(short8*)(pout + (size_t)orow * R + r0 + k0) = v;
    }
}

// ================= fused prep: router partials + gup transpose =================
// blocks [0,512):    router partial logits (4 waves/block) + x->bf16
// blocks [512,1536): gup [E][1024][1024] -> gupT [E][n(perm)][k] bf16
__global__ __launch_bounds__(256) void prep_kernel(
    const float* __restrict__ x, const float* __restrict__ rw,
    const float* __restrict__ gup,
    double* __restrict__ part, unsigned short* __restrict__ xbf,
    unsigned short* __restrict__ gupT)
{
    __shared__ __align__(16) char smem[33792];
    int bid = blockIdx.x;
    int tid = threadIdx.x;

    if (bid >= 512) {
        int i = bid - 512;                 // gup: e(16) x ktile(4) x ntile(16)
        do_transpose256(gup, gupT, HDIM, F2, 1, i >> 6, i & 15, (i >> 4) & 3, smem, tid);
        return;
    }

    // ---- router partials: 512 blocks x 4 waves ----
    int idx = bid;
    int w = tid >> 6;
    int lane = tid & 63;
    int tt = lane & 15, eg = lane >> 4;
    int t0 = idx * 16;
    int hbase = w * 256;

    float* sx  = (float*)(smem + w * 8448);           // [16][68]
    float* srw = (float*)(smem + w * 8448 + 4352);    // [64][16]

    double acc[4] = {0.0, 0.0, 0.0, 0.0};

    for (int hc = 0; hc < 4; ++hc) {
        int h0 = hbase + hc * 64;
        __syncthreads();
#pragma unroll
        for (int j = 0; j < 4; ++j) {
            int fidx = j * 64 + lane;
            int t = fidx >> 4, c4 = (fidx & 15) * 4;
            float4 v = *(const float4*)(x + (size_t)(t0 + t) * HDIM + h0 + c4);
            *(float4*)&sx[t * 68 + c4] = v;
            short4v s;
            s[0] = (short)f2bf(v.x); s[1] = (short)f2bf(v.y);
            s[2] = (short)f2bf(v.z); s[3] = (short)f2bf(v.w);
            *(short4v*)(xbf + (size_t)(t0 + t) * HDIM + h0 + c4) = s;
        }
#pragma unroll
        for (int j = 0; j < 4; ++j) {
            int ridx = j * 64 + lane;
            int h = ridx >> 2, e4 = (ridx & 3) * 4;
            float4 v = *(const float4*)(rw + (size_t)(h0 + h) * NE + e4);
            *(float4*)&srw[h * 16 + e4] = v;
        }
        __syncthreads();
#pragma unroll 8
        for (int j = 0; j < 64; ++j) {
            float xv = sx[tt * 68 + j];
            float4 wv = *(const float4*)&srw[j * 16 + eg * 4];
            double xd = (double)xv;
            acc[0] += xd * (double)wv.x;
            acc[1] += xd * (double)wv.y;
            acc[2] += xd * (double)wv.z;
            acc[3] += xd * (double)wv.w;
        }
    }
#pragma unroll
    for (int q = 0; q < 4; ++q)
        part[(size_t)(w * NE + eg * 4 + q) * TOK + t0 + tt] = acc[q];
}

// ===== router phase B: combine, top-2, softmax, aggregated scatter + inverse map =====
__global__ __launch_bounds__(256) void router_combine_kernel(
    const double* __restrict__ part,
    int* __restrict__ counts, int* __restrict__ toks, float* __restrict__ wgts,
    unsigned short* __restrict__ inv)
{
    __shared__ int lhist[NE];
    __shared__ int lbase[NE];
    int tid = threadIdx.x;
    int t = blockIdx.x * 256 + tid;
    if (tid < NE) lhist[tid] = 0;
    __syncthreads();

    double acc[NE];
#pragma unroll
    for (int e = 0; e < NE; ++e)
        acc[e] = part[(size_t)(0 * NE + e) * TOK + t]
               + part[(size_t)(1 * NE + e) * TOK + t]
               + part[(size_t)(2 * NE + e) * TOK + t]
               + part[(size_t)(3 * NE + e) * TOK + t];

    int i0 = 0; double v0 = acc[0];
#pragma unroll
    for (int e = 1; e < NE; ++e) if (acc[e] > v0) { v0 = acc[e]; i0 = e; }
    int i1 = -1; double v1 = -1e300;
#pragma unroll
    for (int e = 0; e < NE; ++e) if (e != i0 && acc[e] > v1) { v1 = acc[e]; i1 = e; }
    double e1 = exp(v1 - v0);
    float w0 = (float)(1.0 / (1.0 + e1));
    float w1 = (float)(e1 / (1.0 + e1));

    int r0 = atomicAdd(&lhist[i0], 1);
    int r1 = atomicAdd(&lhist[i1], 1);
    __syncthreads();
    if (tid < NE) lbase[tid] = atomicAdd(&counts[tid], lhist[tid]);
    __syncthreads();
    int p0 = lbase[i0] + r0; if (p0 > 2047) p0 = 2047;
    int p1 = lbase[i1] + r1; if (p1 > 2047) p1 = 2047;
    toks[i0 * CAP + p0] = t; wgts[i0 * CAP + p0] = w0;
    toks[i1 * CAP + p1] = t; wgts[i1 * CAP + p1] = w1;
    inv[2 * t]     = (unsigned short)((i0 << 11) | p0);
    inv[2 * t + 1] = (unsigned short)((i1 << 11) | p1);
}

// ===== 3-buffer counted-vmcnt K-loop (T3/T4, prefetch depth 2) — R8-verified =====
#define KLOOP_BODY(NT, KOFF)                                                          \
    int c0 = 0;                                                                       \
    for (int kb = 0; kb < (NT); ++kb) {                                               \
        if (kb + 2 < (NT)) {                                                          \
            int cpre = c0 + 2; if (cpre >= 3) cpre -= 3;                              \
            _Pragma("unroll")                                                         \
            for (int i = 0; i < 2; ++i) {                                             \
                GLD_LDS16(gaA[i] + (kb + 2) * (KOFF), &As[cpre][w * 32 + i * 16][0]); \
                GLD_LDS16(gaB[i] + (kb + 2) * (KOFF), &Bs[cpre][w * 32 + i * 16][0]); \
            }                                                                         \
            asm volatile("s_waitcnt vmcnt(8)" ::: "memory");                          \
        } else if (kb + 1 < (NT)) {                                                   \
            asm volatile("s_waitcnt vmcnt(4)" ::: "memory");                          \
        } else {                                                                      \
            asm volatile("s_waitcnt vmcnt(0)" ::: "memory");                          \
        }                                                                             \
        __builtin_amdgcn_sched_barrier(0);                                            \
        __builtin_amdgcn_s_barrier();                                                 \
        __builtin_amdgcn_sched_barrier(0);                                            \
        short8 af[4], bfr[4];                                                         \
        _Pragma("unroll")                                                             \
        for (int m = 0; m < 4; ++m) af[m] = *(const short8*)&As[c0][wr * 64 + m * 16 + lr][slt]; \
        _Pragma("unroll")                                                             \
        for (int n = 0; n < 4; ++n) bfr[n] = *(const short8*)&Bs[c0][wc * 64 + n * 16 + lr][slt]; \
        _Pragma("unroll")                                                             \
        for (int m = 0; m < 4; ++m)                                                   \
            _Pragma("unroll")                                                         \
            for (int n = 0; n < 4; ++n)                                               \
                acc[m][n] = __builtin_amdgcn_mfma_f32_16x16x32_bf16(af[m], bfr[n], acc[m][n], 0, 0, 0); \
        asm volatile("s_waitcnt lgkmcnt(0)" ::: "memory");                            \
        __builtin_amdgcn_sched_barrier(0);                                            \
        __builtin_amdgcn_s_barrier();                                                 \
        __builtin_amdgcn_sched_barrier(0);                                            \
        c0 = (c0 + 1 == 3) ? 0 : c0 + 1;                                              \
    }

#define KLOOP_PROLOGUE(KOFF)                                                          \
    _Pragma("unroll")                                                                 \
    for (int i = 0; i < 2; ++i) {                                                     \
        GLD_LDS16(gaA[i], &As[0][w * 32 + i * 16][0]);                                \
        GLD_LDS16(gaB[i], &Bs[0][w * 32 + i * 16][0]);                                \
    }                                                                                 \
    _Pragma("unroll")                                                                 \
    for (int i = 0; i < 2; ++i) {                                                     \
        GLD_LDS16(gaA[i] + (KOFF), &As[1][w * 32 + i * 16][0]);                       \
        GLD_LDS16(gaB[i] + (KOFF), &Bs[1][w * 32 + i * 16][0]);                       \
    }

// ------- GEMM1 (+ fused dwn-transpose blocks): x_bf @ gupT^T + bias -> act (bf16) -------
// blocks [0,2048): GEMM1; blocks [2048,2560): dwn [E][512][1024] -> dwnT (overlapped BW work)
__global__ __launch_bounds__(256) void gemm1_kernel(
    const unsigned short* __restrict__ xb, const unsigned short* __restrict__ gupT,
    const float* __restrict__ gub,
    const int* __restrict__ counts, const int* __restrict__ toks,
    unsigned short* __restrict__ act, const unsigned short* __restrict__ zp,
    const float* __restrict__ dwn, unsigned short* __restrict__ dwnT)
{
    __shared__ __align__(16) char smem[49664];
    int b = blockIdx.x;
    int tid = threadIdx.x;

    if (b >= 2048) {
        int i = b - 2048;                  // dwn: e(16) x ktile(2) x ntile(16)
        do_transpose256(dwn, dwnT, NI, HDIM, 0, i >> 5, i & 15, (i >> 4) & 1, smem, tid);
        return;
    }

    unsigned short (*As)[128][32] = (unsigned short (*)[128][32])smem;              // 24576 B
    unsigned short (*Bs)[128][32] = (unsigned short (*)[128][32])(smem + 24576);    // 24576 B
    int* rtok = (int*)(smem + 49152);                                               // 512 B

    int e = b & 15;
    int j = b >> 4;
    int nt = j & 7;
    int mt = j >> 3;
    int cnt = counts[e];
    int row0 = mt * 128;
    if (row0 >= cnt) return;
    int n0 = nt * 128;

    int lane = tid & 63;
    int w = tid >> 6;
    int wr = w >> 1, wc = w & 1;
    int lr = lane & 15, lg = lane >> 4;

    if (tid < 128) {
        int p = row0 + tid;
        rtok[tid] = (p < cnt) ? toks[e * CAP + p] : -1;
    }
    __syncthreads();

    int srow = lane >> 2;
    int scol = (((lane & 3) ^ ((lane >> 3) & 3)) * 8);
    int slt = (lg ^ ((lr >> 1) & 3)) * 8;

    const unsigned short* gaA[2];
    const unsigned short* gaB[2];
    const unsigned short* gupE = gupT + (size_t)e * HDIM * F2;
#pragma unroll
    for (int i = 0; i < 2; ++i) {
        int arow = w * 32 + i * 16 + srow;
        int tk = rtok[arow];
        gaA[i] = (tk >= 0) ? (xb + (size_t)tk * HDIM + scol) : (zp + scol);
        int brow = n0 + w * 32 + i * 16 + srow;
        gaB[i] = gupE + (size_t)brow * HDIM + scol;
    }

    f32x4 acc[4][4];
#pragma unroll
    for (int m = 0; m < 4; ++m)
#pragma unroll
        for (int n = 0; n < 4; ++n) acc[m][n] = (f32x4){0.f, 0.f, 0.f, 0.f};

    KLOOP_PROLOGUE(32)
    KLOOP_BODY(HDIM / 32, 32)

    // epilogue: permuted B rows => acc[m][2q]=gate, acc[m][2q+1]=up of SAME feature, same lane
    unsigned short* actE = act + (size_t)e * CAP2 * NI;
    int fbase = nt * 64 + wc * 32;
#pragma unroll
    for (int q = 0; q < 2; ++q) {
        int f = fbase + q * 16 + lr;
        float bg = gub[e * F2 + 2 * f];
        float bu = gub[e * F2 + 2 * f + 1];
#pragma unroll
        for (int m = 0; m < 4; ++m) {
#pragma unroll
            for (int r = 0; r < 4; ++r) {
                float gate = acc[m][2 * q][r] + bg;
                float up   = acc[m][2 * q + 1][r] + bu;
                gate = fminf(gate, LIMIT);
                up   = fminf(fmaxf(up, -LIMIT), LIMIT);
                float glu = gate / (1.0f + __expf(-ALPHA * gate));
                float av  = (up + 1.0f) * glu;
                int row = row0 + wr * 64 + m * 16 + lg * 4 + r;
                actE[(size_t)row * NI + f] = f2bf(av);
            }
        }
    }
}

// ------- GEMM2 (tier A): act @ dwnT^T, *score, +bias -> compact bf16 y[base[e]+p][HDIM] -------
__global__ __launch_bounds__(256) void gemm2_y_kernel(
    const unsigned short* __restrict__ act, const unsigned short* __restrict__ dwnT,
    const float* __restrict__ dwb,
    const int* __restrict__ counts, const float* __restrict__ wgts,
    unsigned short* __restrict__ y)
{
    int b = blockIdx.x;
    int e = b & 15;
    int j = b >> 4;
    int nt = j & 7;
    int mt = j >> 3;
    int cnt = counts[e];
    int row0 = mt * 128;
    if (row0 >= cnt) return;
    int n0 = nt * 128;

    int base_e = 0;
#pragma unroll
    for (int q = 0; q < NE; ++q) base_e += (q < e) ? counts[q] : 0;

    __shared__ __align__(16) unsigned short As[3][128][32];
    __shared__ __align__(16) unsigned short Bs[3][128][32];
    __shared__ float rwgt[128];

    int tid = threadIdx.x;
    int lane = tid & 63;
    int w = tid >> 6;
    int wr = w >> 1, wc = w & 1;
    int lr = lane & 15, lg = lane >> 4;

    if (tid < 128) {
        int p = row0 + tid;
        rwgt[tid] = (p < cnt) ? wgts[e * CAP + p] : 0.0f;
    }
    __syncthreads();

    int srow = lane >> 2;
    int scol = (((lane & 3) ^ ((lane >> 3) & 3)) * 8);
    int slt = (lg ^ ((lr >> 1) & 3)) * 8;

    const unsigned short* gaA[2];
    const unsigned short* gaB[2];
    const unsigned short* actE = act + (size_t)e * CAP2 * NI;
    const unsigned short* dwnE = dwnT + (size_t)e * HDIM * NI;
#pragma unroll
    for (int i = 0; i < 2; ++i) {
        int arow = row0 + w * 32 + i * 16 + srow;
        gaA[i] = actE + (size_t)arow * NI + scol;
        int brow = n0 + w * 32 + i * 16 + srow;
        gaB[i] = dwnE + (size_t)brow * NI + scol;
    }

    f32x4 acc[4][4];
#pragma unroll
    for (int m = 0; m < 4; ++m)
#pragma unroll
        for (int n = 0; n < 4; ++n) acc[m][n] = (f32x4){0.f, 0.f, 0.f, 0.f};

    KLOOP_PROLOGUE(32)
    KLOOP_BODY(NI / 32, 32)

    unsigned short* yB = y + (size_t)(base_e + row0) * HDIM;
#pragma unroll
    for (int n = 0; n < 4; ++n) {
        int hc = n0 + wc * 64 + n * 16 + lr;
        float db = dwb[e * HDIM + hc];
#pragma unroll
        for (int m = 0; m < 4; ++m) {
#pragma unroll
            for (int r = 0; r < 4; ++r) {
                int rl = wr * 64 + m * 16 + lg * 4 + r;
                if (row0 + rl < cnt)
                    yB[(size_t)rl * HDIM + hc] = f2bf(rwgt[rl] * (acc[m][n][r] + db));
            }
        }
    }
}

// ------- out combine: out[t] = y[slot0] + y[slot1]; bf16 reads, coalesced, no atomics -------
__global__ __launch_bounds__(256) void out_combine_kernel(
    const unsigned short* __restrict__ y, const unsigned short* __restrict__ inv,
    const int* __restrict__ counts, float* __restrict__ out)
{
    __shared__ int sbase[NE];
    int tid = threadIdx.x;
    int t = blockIdx.x;
    if (tid == 0) {
        int s = 0;
#pragma unroll
        for (int e = 0; e < NE; ++e) { sbase[e] = s; s += counts[e]; }
    }
    __syncthreads();
    unsigned short v0 = inv[2 * t], v1 = inv[2 * t + 1];
    int s0 = sbase[v0 >> 11] + (v0 & 2047);
    int s1 = sbase[v1 >> 11] + (v1 & 2047);
    short4v a = *(const short4v*)(y + (size_t)s0 * HDIM + tid * 4);
    short4v c = *(const short4v*)(y + (size_t)s1 * HDIM + tid * 4);
    float4 o;
    o.x = bf2f((unsigned short)a[0]) + bf2f((unsigned short)c[0]);
    o.y = bf2f((unsigned short)a[1]) + bf2f((unsigned short)c[1]);
    o.z = bf2f((unsigned short)a[2]) + bf2f((unsigned short)c[2]);
    o.w = bf2f((unsigned short)a[3]) + bf2f((unsigned short)c[3]);
    *(float4*)(out + (size_t)t * HDIM + tid * 4) = o;
}

// ================= fallback path kernels (round-1 style, small ws) =================
__global__ __launch_bounds__(256) void router_kernel(
    const float* __restrict__ x, const float* __restrict__ rw,
    int* __restrict__ counts, int* __restrict__ toks, float* __restrict__ wgts)
{
    int gwave = (int)((blockIdx.x * 256 + threadIdx.x) >> 6);
    int lane = threadIdx.x & 63;
    if (gwave >= TOK) return;
    const float* xr = x + (size_t)gwave * HDIM;
    double acc[NE];
#pragma unroll
    for (int e = 0; e < NE; ++e) acc[e] = 0.0;
    for (int i = 0; i < HDIM / 64; ++i) {
        int h = i * 64 + lane;
        double xv = (double)xr[h];
        const float* r = rw + (size_t)h * NE;
#pragma unroll
        for (int e = 0; e < NE; ++e) acc[e] += xv * (double)r[e];
    }
#pragma unroll
    for (int e = 0; e < NE; ++e) {
        double v = acc[e];
#pragma unroll
        for (int off = 32; off > 0; off >>= 1) v += __shfl_xor(v, off);
        acc[e] = v;
    }
    if (lane == 0) {
        int i0 = 0; double v0 = acc[0];
#pragma unroll
        for (int e = 1; e < NE; ++e) if (acc[e] > v0) { v0 = acc[e]; i0 = e; }
        int i1 = -1; double v1 = -1e300;
#pragma unroll
        for (int e = 0; e < NE; ++e) if (e != i0 && acc[e] > v1) { v1 = acc[e]; i1 = e; }
        double e1 = exp(v1 - v0);
        float w0 = (float)(1.0 / (1.0 + e1));
        float w1 = (float)(e1 / (1.0 + e1));
        int p0 = atomicAdd(&counts[i0], 1);
        toks[i0 * CAP + p0] = gwave; wgts[i0 * CAP + p0] = w0;
        int p1 = atomicAdd(&counts[i1], 1);
        toks[i1 * CAP + p1] = gwave; wgts[i1 * CAP + p1] = w1;
    }
}

__global__ __launch_bounds__(256) void moe_kernel(
    const float* __restrict__ x,
    const float* __restrict__ gup, const float* __restrict__ gub,
    const float* __restrict__ dwn, const float* __restrict__ dwb,
    const int* __restrict__ counts, const int* __restrict__ toks,
    const float* __restrict__ wgts, float* __restrict__ out)
{
    int e = blockIdx.y;
    int cnt = counts[e];
    int row0 = blockIdx.x * 64;
    if (row0 >= cnt) return;

    __shared__ __align__(16) unsigned short sA[64][40];
    __shared__ __align__(16) unsigned short sB[64][40];
    __shared__ __align__(16) unsigned short sAct[64][520];
    __shared__ int   rtok[64];
    __shared__ float rwgt[64];

    int tid = threadIdx.x;
    if (tid < 64) {
        int idx = row0 + tid;
        bool v = idx < cnt;
        rtok[tid] = v ? toks[e * CAP + idx] : -1;
        rwgt[tid] = v ? wgts[e * CAP + idx] : 0.0f;
    }
    __syncthreads();

    int lane = tid & 63;
    int w = tid >> 6;
    int wr = w >> 1, wc = w & 1;
    int lr = lane & 15, lg = lane >> 4;
    int ar = tid >> 2, ac0 = (tid & 3) * 8;
    int bk = tid >> 3, bf0 = (tid & 7) * 8;
    const float* gupE = gup + (size_t)e * HDIM * F2;

    for (int nb = 0; nb < F2 / 64; ++nb) {
        f32x4 acc[2][2];
#pragma unroll
        for (int mi = 0; mi < 2; ++mi)
#pragma unroll
            for (int ni = 0; ni < 2; ++ni) acc[mi][ni] = (f32x4){0.f, 0.f, 0.f, 0.f};
        for (int kb = 0; kb < HDIM / 32; ++kb) {
            __syncthreads();
            {
                int tk = rtok[ar];
                short8 vv = {0,0,0,0,0,0,0,0};
                if (tk >= 0) {
                    const float* p = x + (size_t)tk * HDIM + kb * 32 + ac0;
                    float4 u0 = *(const float4*)(p); float4 u1 = *(const float4*)(p + 4);
                    vv[0]=(short)f2bf(u0.x); vv[1]=(short)f2bf(u0.y); vv[2]=(short)f2bf(u0.z); vv[3]=(short)f2bf(u0.w);
                    vv[4]=(short)f2bf(u1.x); vv[5]=(short)f2bf(u1.y); vv[6]=(short)f2bf(u1.z); vv[7]=(short)f2bf(u1.w);
                }
                *(short8*)&sA[ar][ac0] = vv;
            }
            {
                const float* p = gupE + (size_t)(kb * 32 + bk) * F2 + nb * 64 + bf0;
                float4 u0 = *(const float4*)(p); float4 u1 = *(const float4*)(p + 4);
                sB[bf0+0][bk]=f2bf(u0.x); sB[bf0+1][bk]=f2bf(u0.y); sB[bf0+2][bk]=f2bf(u0.z); sB[bf0+3][bk]=f2bf(u0.w);
                sB[bf0+4][bk]=f2bf(u1.x); sB[bf0+5][bk]=f2bf(u1.y); sB[bf0+6][bk]=f2bf(u1.z); sB[bf0+7][bk]=f2bf(u1.w);
            }
            __syncthreads();
            short8 a0 = *(const short8*)&sA[wr*32+lr][lg*8];
            short8 a1 = *(const short8*)&sA[wr*32+16+lr][lg*8];
            short8 b0 = *(const short8*)&sB[wc*32+lr][lg*8];
            short8 b1 = *(const short8*)&sB[wc*32+16+lr][lg*8];
            acc[0][0] = __builtin_amdgcn_mfma_f32_16x16x32_bf16(a0,b0,acc[0][0],0,0,0);
            acc[0][1] = __builtin_amdgcn_mfma_f32_16x16x32_bf16(a0,b1,acc[0][1],0,0,0);
            acc[1][0] = __builtin_amdgcn_mfma_f32_16x16x32_bf16(a1,b0,acc[1][0],0,0,0);
            acc[1][1] = __builtin_amdgcn_mfma_f32_16x16x32_bf16(a1,b1,acc[1][1],0,0,0);
        }
#pragma unroll
        for (int ni = 0; ni < 2; ++ni) {
            int fc = nb * 64 + wc * 32 + ni * 16 + lr;
            float bias = gub[e * F2 + fc];
#pragma unroll
            for (int mi = 0; mi < 2; ++mi)
#pragma unroll
                for (int r = 0; r < 4; ++r) {
                    float gu = acc[mi][ni][r] + bias;
                    float other = __shfl_xor(gu, 1);
                    float gate = (lr & 1) ? other : gu;
                    float up   = (lr & 1) ? gu : other;
                    gate = fminf(gate, LIMIT);
                    up = fminf(fmaxf(up, -LIMIT), LIMIT);
                    float glu = gate / (1.0f + __expf(-ALPHA * gate));
                    float av = (up + 1.0f) * glu;
                    if (!(lr & 1)) sAct[wr*32+mi*16+lg*4+r][fc >> 1] = f2bf(av);
                }
        }
    }
    __syncthreads();

    const float* dwnE = dwn + (size_t)e * NI * HDIM;
    int tks[2][4]; float wvs[2][4];
#pragma unroll
    for (int mi = 0; mi < 2; ++mi)
#pragma unroll
        for (int r = 0; r < 4; ++r) {
            int row = wr*32 + mi*16 + lg*4 + r;
            tks[mi][r] = rtok[row]; wvs[mi][r] = rwgt[row];
        }
    for (int nb = 0; nb < HDIM / 64; ++nb) {
        f32x4 acc[2][2];
#pragma unroll
        for (int mi = 0; mi < 2; ++mi)
#pragma unroll
            for (int ni = 0; ni < 2; ++ni) acc[mi][ni] = (f32x4){0.f,0.f,0.f,0.f};
        for (int kb = 0; kb < NI / 32; ++kb) {
            __syncthreads();
            {
                const float* p = dwnE + (size_t)(kb*32 + bk) * HDIM + nb*64 + bf0;
                float4 u0 = *(const float4*)(p); float4 u1 = *(const float4*)(p + 4);
                sB[bf0+0][bk]=f2bf(u0.x); sB[bf0+1][bk]=f2bf(u0.y); sB[bf0+2][bk]=f2bf(u0.z); sB[bf0+3][bk]=f2bf(u0.w);
                sB[bf0+4][bk]=f2bf(u1.x); sB[bf0+5][bk]=f2bf(u1.y); sB[bf0+6][bk]=f2bf(u1.z); sB[bf0+7][bk]=f2bf(u1.w);
            }
            __syncthreads();
            short8 a0 = *(const short8*)&sAct[wr*32+lr][kb*32+lg*8];
            short8 a1 = *(const short8*)&sAct[wr*32+16+lr][kb*32+lg*8];
            short8 b0 = *(const short8*)&sB[wc*32+lr][lg*8];
            short8 b1 = *(const short8*)&sB[wc*32+16+lr][lg*8];
            acc[0][0] = __builtin_amdgcn_mfma_f32_16x16x32_bf16(a0,b0,acc[0][0],0,0,0);
            acc[0][1] = __builtin_amdgcn_mfma_f32_16x16x32_bf16(a0,b1,acc[0][1],0,0,0);
            acc[1][0] = __builtin_amdgcn_mfma_f32_16x16x32_bf16(a1,b0,acc[1][0],0,0,0);
            acc[1][1] = __builtin_amdgcn_mfma_f32_16x16x32_bf16(a1,b1,acc[1][1],0,0,0);
        }
#pragma unroll
        for (int ni = 0; ni < 2; ++ni) {
            int hc = nb*64 + wc*32 + ni*16 + lr;
            float db = dwb[e * HDIM + hc];
#pragma unroll
            for (int mi = 0; mi < 2; ++mi)
#pragma unroll
                for (int r = 0; r < 4; ++r) {
                    int tk = tks[mi][r];
                    if (tk >= 0)
                        atomicAdd(out + (size_t)tk * HDIM + hc, wvs[mi][r] * (acc[mi][ni][r] + db));
                }
        }
    }
}

extern "C" void kernel_launch(void* const* d_in, const int* in_sizes, int n_in,
                              void* d_out, int out_size, void* d_ws, size_t ws_size,
                              hipStream_t stream) {
    const float* x   = (const float*)d_in[0];
    const float* rw  = (const float*)d_in[1];
    const float* gup = (const float*)d_in[2];
    const float* gub = (const float*)d_in[3];
    const float* dwn = (const float*)d_in[4];
    const float* dwb = (const float*)d_in[5];
    float* out = (float*)d_out;

    // ---- ws layout ----
    const size_t OFF_COUNTS = 0;                                   // 256 B
    const size_t OFF_ZP     = 256;                                 // 4 KB zero page
    const size_t OFF_INV    = 4352;                                // 32 KB
    const size_t OFF_TOKS   = OFF_INV  + (size_t)TOK * 2 * 2;
    const size_t OFF_WGTS   = OFF_TOKS + (size_t)NE * CAP * 4;
    const size_t OFF_DWNT   = OFF_WGTS + (size_t)NE * CAP * 4;
    const size_t OFF_ACT    = OFF_DWNT + (size_t)NE * NI * HDIM * 2;   // part (4MB) aliases here
    const size_t OFF_XBF    = OFF_ACT  + (size_t)NE * CAP2 * NI * 2;
    const size_t OFF_GUPT   = OFF_XBF  + (size_t)TOK * HDIM * 2;
    const size_t REQ_B      = OFF_GUPT + (size_t)NE * HDIM * F2 * 2;
    const size_t OFF_Y      = OFF_XBF;                             // aliases xbf+gupT (dead after gemm1)
    const size_t REQ_A      = OFF_Y + (size_t)2 * TOK * HDIM * 2;  // 32 MB compact bf16 y

    if (ws_size >= REQ_B) {
        int*            counts = (int*)((char*)d_ws + OFF_COUNTS);
        unsigned short* zp     = (unsigned short*)((char*)d_ws + OFF_ZP);
        unsigned short* inv    = (unsigned short*)((char*)d_ws + OFF_INV);
        int*            toks   = (int*)((char*)d_ws + OFF_TOKS);
        float*          wgts   = (float*)((char*)d_ws + OFF_WGTS);
        unsigned short* dwnT   = (unsigned short*)((char*)d_ws + OFF_DWNT);
        unsigned short* act    = (unsigned short*)((char*)d_ws + OFF_ACT);
        double*         part   = (double*)((char*)d_ws + OFF_ACT);
        unsigned short* xbf    = (unsigned short*)((char*)d_ws + OFF_XBF);
        unsigned short* gupT   = (unsigned short*)((char*)d_ws + OFF_GUPT);
        unsigned short* y      = (unsigned short*)((char*)d_ws + OFF_Y);

        hipMemsetAsync(d_ws, 0, 4352, stream);   // counts + zero page

        // prep: router partials (512 blocks) + gup transpose (1024 blocks)
        prep_kernel<<<512 + 1024, 256, 0, stream>>>(x, rw, gup, part, xbf, gupT);

        router_combine_kernel<<<TOK / 256, 256, 0, stream>>>(part, counts, toks, wgts, inv);

        // gemm1 (2048 blocks) + fused dwn transpose (512 blocks, BW work overlapped)
        gemm1_kernel<<<2048 + 512, 256, 0, stream>>>(xbf, gupT, gub, counts, toks, act, zp,
                                                     dwn, dwnT);
        int g2 = (CAP2 / 128) * (HDIM / 128) * NE;   // 2048

        if (ws_size >= REQ_A) {
            gemm2_y_kernel<<<g2, 256, 0, stream>>>(act, dwnT, dwb, counts, wgts, y);
            out_combine_kernel<<<TOK, 256, 0, stream>>>(y, inv, counts, out);
        } else {
            hipMemsetAsync(d_out, 0, (size_t)out_size * sizeof(float), stream);
            out_combine_kernel<<<TOK, 256, 0, stream>>>(y, inv, counts, out);
        }
    } else {
        // fallback: round-1 path (~1.1 MB of ws)
        int*   counts = (int*)d_ws;
        int*   toks   = (int*)((char*)d_ws + 64);
        float* wgts   = (float*)((char*)d_ws + 64 + (size_t)NE * CAP * sizeof(int));
        hipMemsetAsync(d_ws, 0, 64, stream);
        hipMemsetAsync(d_out, 0, (size_t)out_size * sizeof(float), stream);
        router_kernel<<<TOK / 4, 256, 0, stream>>>(x, rw, counts, toks, wgts);
        dim3 gm(TOK / 64, NE);
        moe_kernel<<<gm, 256, 0, stream>>>(x, gup, gub, dwn, dwb, counts, toks, wgts, out);
    }
}